// Round 7
// baseline (858.177 us; speedup 1.0000x reference)
//
#include <hip/hip_runtime.h>
#include <stdint.h>

#define NN   8192
#define DIN  256
#define FF   128
#define NF   (NN*FF)          // 1048576
#define SLOPE 0.2f
#define EPSI  1e-5f

typedef float vf4 __attribute__((ext_vector_type(4)));

#if __has_builtin(__builtin_amdgcn_sched_barrier)
#define SCHED_FENCE() __builtin_amdgcn_sched_barrier(0)
#else
#define SCHED_FENCE() asm volatile("" ::: "memory")
#endif

// s_waitcnt imm fields (gfx9+): vmcnt lo [3:0], expcnt [6:4], lgkmcnt [11:8], vmcnt hi [15:14]
#define WAITCNT_VM16_LGKM0 0x4070   // vmcnt(16) lgkmcnt(0) expcnt(7=dontcare)
#define WAITCNT_VM0_LGKM0  0x0070   // vmcnt(0)  lgkmcnt(0)

// ---- workspace layout (float offsets) ----
#define OFF_PROJ   0                       // [2][N][F] f32 (k_gemm->k_sprep), then REUSED as bitmask [N][256] u32 (8 MB)
#define OFF_RESID  (2*NF)                  // [N][F] f32
#define OFF_PACKED (3*NF)                  // [N][F] uint32: lo16=bf16(head0), hi16=bf16(head1)
#define OFF_SS     (4*NF)                  // s_src [2][N]
#define OFF_ST     (OFF_SS + 2*NN)         // s_tgt [2][N]
#define OFF_CSUM   (OFF_ST + 2*NN)         // colsum [2][N]
#define OFF_STATS  (OFF_CSUM + 2*NN)       // S, SS (2 floats; padded to 16)
#define OFF_NTAB   (OFF_STATS + 16)        // float4[N] = {st0, st1, rcp_csum0, rcp_csum1}
#define OFF_VALS   (OFF_NTAB + 4*NN)       // [N][F] f32
#define OFF_WT     (OFF_VALS + NF)         // W_res transposed: [DIN][F]

__device__ __forceinline__ float lrelu(float x) { return x >= 0.f ? x : SLOPE * x; }

__device__ __forceinline__ uint32_t bfpack(float a, float b) {
  uint32_t ua = __float_as_uint(a); ua += 0x7fffu + ((ua >> 16) & 1u);
  uint32_t ub = __float_as_uint(b); ub += 0x7fffu + ((ub >> 16) & 1u);
  return (ua >> 16) | (ub & 0xffff0000u);
}

// ---- K0: transpose W_res [F][DIN] -> Wt [DIN][F] ----
__global__ __launch_bounds__(256) void k_wt(const float* __restrict__ wres, float* __restrict__ wt) {
  int i = blockIdx.x * 256 + threadIdx.x;
  int d = i >> 7, f = i & 127;
  wt[i] = wres[f * DIN + d];
}

// ---- K1: 3 GEMMs M=8192 K=256 N=128 (heads 0,1 -> proj; y==2 -> resid) ----
__global__ __launch_bounds__(256) void k_gemm(const float* __restrict__ x, const float* __restrict__ Wh,
                                              const float* __restrict__ wt, float* __restrict__ proj,
                                              float* __restrict__ resid) {
  const int h = blockIdx.y;
  const float* __restrict__ Wsrc = (h < 2) ? (Wh + h * (DIN * FF)) : wt;
  float* __restrict__ outp = (h < 2) ? (proj + h * NF) : resid;
  const int row0 = blockIdx.x * 64;
  __shared__ float xs[64 * 68];
  const int tid = threadIdx.x;
  const int ft = tid & 15, rt = tid >> 4;
  const int f0 = ft * 8, r0 = rt * 4;
  float acc[4][8];
#pragma unroll
  for (int j = 0; j < 4; ++j)
#pragma unroll
    for (int k = 0; k < 8; ++k) acc[j][k] = 0.f;

  for (int kc = 0; kc < 4; ++kc) {
    const int d0 = kc * 64;
#pragma unroll
    for (int k2 = 0; k2 < 4; ++k2) {
      int i = tid * 4 + k2 * 1024;
      int r = i >> 6, dd = i & 63;
      *(float4*)&xs[r * 68 + dd] = *(const float4*)&x[(row0 + r) * DIN + d0 + dd];
    }
    __syncthreads();
#pragma unroll
    for (int g = 0; g < 16; ++g) {
      const int dd = g * 4;
      float xr[4][4];
#pragma unroll
      for (int j = 0; j < 4; ++j) {
        float4 t = *(const float4*)&xs[(r0 + j) * 68 + dd];
        xr[j][0] = t.x; xr[j][1] = t.y; xr[j][2] = t.z; xr[j][3] = t.w;
      }
#pragma unroll
      for (int i = 0; i < 4; ++i) {
        float4 wa = *(const float4*)&Wsrc[(d0 + dd + i) * FF + f0];
        float4 wb = *(const float4*)&Wsrc[(d0 + dd + i) * FF + f0 + 4];
#pragma unroll
        for (int j = 0; j < 4; ++j) {
          float xx = xr[j][i];
          acc[j][0] += xx * wa.x; acc[j][1] += xx * wa.y; acc[j][2] += xx * wa.z; acc[j][3] += xx * wa.w;
          acc[j][4] += xx * wb.x; acc[j][5] += xx * wb.y; acc[j][6] += xx * wb.z; acc[j][7] += xx * wb.w;
        }
      }
    }
    __syncthreads();
  }
#pragma unroll
  for (int j = 0; j < 4; ++j) {
    int row = row0 + r0 + j;
    *(float4*)&outp[row * FF + f0]     = make_float4(acc[j][0], acc[j][1], acc[j][2], acc[j][3]);
    *(float4*)&outp[row * FF + f0 + 4] = make_float4(acc[j][4], acc[j][5], acc[j][6], acc[j][7]);
  }
}

// ---- K1b: per-node dots s_src/s_tgt (both heads) + bf16 pack of proj ----
__global__ __launch_bounds__(256) void k_sprep(const float* __restrict__ proj, const float* __restrict__ a_src,
                                               const float* __restrict__ a_tgt, float* __restrict__ ss,
                                               float* __restrict__ st, uint32_t* __restrict__ packed) {
  int lane = threadIdx.x & 63, wid = threadIdx.x >> 6;
  int n = blockIdx.x * 4 + wid;
  float2 q0 = *(const float2*)&proj[n * FF + 2 * lane];
  float2 q1 = *(const float2*)&proj[NF + n * FF + 2 * lane];
  float2 as0 = *(const float2*)&a_src[2 * lane];
  float2 at0 = *(const float2*)&a_tgt[2 * lane];
  float2 as1 = *(const float2*)&a_src[FF + 2 * lane];
  float2 at1 = *(const float2*)&a_tgt[FF + 2 * lane];
  float v0 = q0.x * as0.x + q0.y * as0.y;
  float v1 = q0.x * at0.x + q0.y * at0.y;
  float v2 = q1.x * as1.x + q1.y * as1.y;
  float v3 = q1.x * at1.x + q1.y * at1.y;
#pragma unroll
  for (int o = 1; o < 64; o <<= 1) {
    v0 += __shfl_xor(v0, o); v1 += __shfl_xor(v1, o);
    v2 += __shfl_xor(v2, o); v3 += __shfl_xor(v3, o);
  }
  uint2 pk;
  pk.x = bfpack(q0.x, q1.x);
  pk.y = bfpack(q0.y, q1.y);
  *(uint2*)&packed[n * FF + 2 * lane] = pk;
  if (lane == 0) { ss[n] = v0; ss[NN + n] = v2; st[n] = v1; st[NN + n] = v3; }
}

// ---- K2 v5 (k_scan): column-stripe; 8-row load batches; ss preloaded into registers
// (readlane per row — no uniform loads on the critical path); colsum in registers,
// 2 atomics/thread. Bitmask word = m*256 + n/32 (sorted layout). ----
__global__ __launch_bounds__(256) void k_scan(const float* __restrict__ mask, float* __restrict__ maskout,
                                              const float* __restrict__ ss, const float* __restrict__ st,
                                              float* __restrict__ csum, uint32_t* __restrict__ bitmask) {
  const int tid = threadIdx.x;
  const int lane = tid & 63, wv = tid >> 6;
  const int n = blockIdx.x * 256 + tid;
  const int m0 = blockIdx.y * 128;
  const int wbase = blockIdx.x * 8 + wv * 2;     // word-pair index within a row
  const float st0 = st[n], st1 = st[NN + n];
  // preload the block's 128 ss values (both heads) into 4 registers across lanes
  const float ssA = ss[m0 + lane],      ssB = ss[m0 + 64 + lane];
  const float ssC = ss[NN + m0 + lane], ssD = ss[NN + m0 + 64 + lane];
  float c0 = 0.f, c1 = 0.f;

  for (int i = 0; i < 128; i += 8) {
    float v[8];
#pragma unroll
    for (int r = 0; r < 8; ++r)
      v[r] = __builtin_nontemporal_load(&mask[(size_t)(m0 + i + r) * NN + n]);
#pragma unroll
    for (int r = 0; r < 8; ++r) {
      const int m = m0 + i + r;
      __builtin_nontemporal_store(v[r], &maskout[(size_t)m * NN + n]);
      bool e = v[r] > -0.5e9f;                   // edges exactly 0.0f, non-edges -1e9
      unsigned long long bm = __ballot(e);
      if (lane == 0)
        *(uint2*)&bitmask[m * 256 + wbase] = make_uint2((uint32_t)bm, (uint32_t)(bm >> 32));
      const int ri = i + r;                      // uniform row index within block
      float s0 = __uint_as_float(__builtin_amdgcn_readlane(
                   __float_as_uint(ri < 64 ? ssA : ssB), ri & 63));
      float s1 = __uint_as_float(__builtin_amdgcn_readlane(
                   __float_as_uint(ri < 64 ? ssC : ssD), ri & 63));
      float w0 = __expf(lrelu(s0 + st0));
      float w1 = __expf(lrelu(s1 + st1));
      c0 += e ? w0 : 0.f;
      c1 += e ? w1 : 0.f;
    }
  }
  atomicAdd(&csum[n], c0);
  atomicAdd(&csum[NN + n], c1);
}

// ---- K2c: pack per-column table {st0, st1, 1/csum0, 1/csum1} ----
__global__ __launch_bounds__(256) void k_ntab(const float* __restrict__ st, const float* __restrict__ csum,
                                              float4* __restrict__ ntab) {
  int i = blockIdx.x * 256 + threadIdx.x;
  ntab[i] = make_float4(st[i], st[NN + i], 1.f / csum[i], 1.f / csum[NN + i]);
}

// ---- K3 v6: wave-per-row; LDS-DMA double-buffered gather.
// Phase 1: decode sorted bitmask -> LDS edge list. Phase 2: per 64-edge tile,
// lanes compute weights (LDS wbuf); 8-edge sub-batches are DMA'd to LDS via
// global_load_lds (2x 256B per edge, zero VGPR cost, deep outstanding queue),
// pipelined with s_waitcnt vmcnt(16); consume via ds_read_b64 per lane. ----
__global__ __launch_bounds__(256) void k_vals(const uint32_t* __restrict__ bitmask, const uint32_t* __restrict__ packed,
                                              const float4* __restrict__ ntab, const float* __restrict__ ss,
                                              float* __restrict__ vals, float* __restrict__ stats) {
  __shared__ uint16_t el[4][1024];        // 8 KB: per-wave edge list
  __shared__ uint32_t dbuf[4][2][8 * 128];// 32 KB: per-wave double-buffered edge data (8 edges x 512B)
  __shared__ float2   wbuf[4][64];        // 2 KB: per-wave per-tile weights
  const int lane = threadIdx.x & 63, wid = threadIdx.x >> 6;
  const int m = blockIdx.x * 4 + wid;

  // ---- phase 1: decode bitmask row m (sorted columns) ----
  uint4 wv = ((const uint4*)(bitmask + m * 256))[lane];   // cols [128*lane, 128*lane+128)
  uint32_t wd[4] = {wv.x, wv.y, wv.z, wv.w};
  int cnt = __popc(wd[0]) + __popc(wd[1]) + __popc(wd[2]) + __popc(wd[3]);
  int pre = cnt;
#pragma unroll
  for (int o = 1; o < 64; o <<= 1) { int t = __shfl_up(pre, o); if (lane >= o) pre += t; }
  int nE = __shfl(pre, 63);
  int base = pre - cnt;
#pragma unroll
  for (int u = 0; u < 4; ++u) {
    uint32_t w = wd[u];
    int nbase = lane * 128 + u * 32;
    while (w) {
      int b = __builtin_ctz(w); w &= w - 1;
      if (base < 1024) el[wid][base] = (uint16_t)(nbase + b);
      ++base;
    }
  }
  if (nE > 1024) nE = 1024;
  __builtin_amdgcn_wave_barrier();

  // ---- phase 2 ----
  const float ss0 = ss[m], ss1 = ss[NN + m];
  float a00 = 0.f, a01 = 0.f, a10 = 0.f, a11 = 0.f;   // f=2*lane, f=2*lane+1 (h0,h1 each)
  const char* __restrict__ pb = (const char*)packed;
  uint32_t* __restrict__ db0 = &dbuf[wid][0][0];
  uint32_t* __restrict__ db1 = &dbuf[wid][1][0];

  for (int t = 0; t < nE; t += 64) {
    // per-lane weight + offset for this tile's 64 edges
    int e = t + lane;
    float w0 = 0.f, w1 = 0.f; uint32_t off = 0;
    if (e < nE) {
      int n = el[wid][e];
      float4 tb = ntab[n];
      w0 = __expf(lrelu(ss0 + tb.x)) * tb.z;
      w1 = __expf(lrelu(ss1 + tb.y)) * tb.w;
      off = (uint32_t)n << 9;
    }
    wbuf[wid][lane] = make_float2(w0, w1);
    __builtin_amdgcn_wave_barrier();

    // DMA issue for sub-batch sb into dbuf[sb&1]: 2x global_load_lds (256B each) per edge
#define ISSUE_SB(sb)                                                                   \
    {                                                                                  \
      uint32_t* dst = ((sb) & 1) ? db1 : db0;                                          \
      _Pragma("unroll")                                                                \
      for (int j = 0; j < 8; ++j) {                                                    \
        uint32_t so = __builtin_amdgcn_readlane(off, (sb) * 8 + j);                    \
        const uint32_t* g = (const uint32_t*)(pb + so) + lane;                         \
        __builtin_amdgcn_global_load_lds(                                              \
            (const __attribute__((address_space(1))) uint32_t*)g,                      \
            (__attribute__((address_space(3))) uint32_t*)&dst[j * 128], 4, 0, 0);      \
        __builtin_amdgcn_global_load_lds(                                              \
            (const __attribute__((address_space(1))) uint32_t*)(g + 64),               \
            (__attribute__((address_space(3))) uint32_t*)&dst[j * 128 + 64], 4, 0, 0); \
      }                                                                                \
    }

    ISSUE_SB(0)
#pragma unroll 1
    for (int sb = 0; sb < 8; ++sb) {
      if (sb < 7) {
        switch (sb + 1) {   // readlane needs constant-foldable lane indices
          case 1: ISSUE_SB(1) break; case 2: ISSUE_SB(2) break; case 3: ISSUE_SB(3) break;
          case 4: ISSUE_SB(4) break; case 5: ISSUE_SB(5) break; case 6: ISSUE_SB(6) break;
          case 7: ISSUE_SB(7) break;
        }
        SCHED_FENCE();
        __builtin_amdgcn_s_waitcnt(WAITCNT_VM16_LGKM0);   // oldest 16 (sub-batch sb) done
        SCHED_FENCE();
      } else {
        SCHED_FENCE();
        __builtin_amdgcn_s_waitcnt(WAITCNT_VM0_LGKM0);
        SCHED_FENCE();
      }
      const uint32_t* src = (sb & 1) ? db1 : db0;
#pragma unroll
      for (int j = 0; j < 8; ++j) {
        float2 w = wbuf[wid][sb * 8 + j];                 // broadcast ds_read_b64
        uint2 d = *(const uint2*)&src[j * 128 + 2 * lane];
        a00 += w.x * __uint_as_float(d.x << 16);
        a10 += w.y * __uint_as_float(d.x & 0xffff0000u);
        a01 += w.x * __uint_as_float(d.y << 16);
        a11 += w.y * __uint_as_float(d.y & 0xffff0000u);
      }
    }
    __builtin_amdgcn_wave_barrier();
#undef ISSUE_SB
  }

  float v0 = 0.5f * (a00 + a10), v1 = 0.5f * (a01 + a11);
  *(float2*)&vals[m * FF + 2 * lane] = make_float2(v0, v1);
  float s = v0 + v1, q = v0 * v0 + v1 * v1;
#pragma unroll
  for (int o = 1; o < 64; o <<= 1) { s += __shfl_xor(s, o); q += __shfl_xor(q, o); }
  if (lane == 0) { atomicAdd(stats, s); atomicAdd(stats + 1, q); }
}

// ---- K5: instance-norm + residual + ELU ----
__global__ __launch_bounds__(256) void k_final(const float* __restrict__ vals, const float* __restrict__ resid,
                                               const float* __restrict__ stats, float* __restrict__ out) {
  int i = (blockIdx.x * 256 + threadIdx.x) * 4;
  float mu = stats[0] * (1.f / NF);
  float var = stats[1] * (1.f / NF) - mu * mu;
  float rs = rsqrtf(var + EPSI);
  float4 v = *(const float4*)&vals[i];
  float4 r = *(const float4*)&resid[i];
  float t0 = (v.x - mu) * rs + r.x;
  float t1 = (v.y - mu) * rs + r.y;
  float t2 = (v.z - mu) * rs + r.z;
  float t3 = (v.w - mu) * rs + r.w;
  float4 o;
  o.x = t0 > 0.f ? t0 : expm1f(t0);
  o.y = t1 > 0.f ? t1 : expm1f(t1);
  o.z = t2 > 0.f ? t2 : expm1f(t2);
  o.w = t3 > 0.f ? t3 : expm1f(t3);
  *(float4*)&out[i] = o;
}

extern "C" void kernel_launch(void* const* d_in, const int* in_sizes, int n_in,
                              void* d_out, int out_size, void* d_ws, size_t ws_size,
                              hipStream_t stream) {
  const float* x     = (const float*)d_in[0];
  const float* mask  = (const float*)d_in[1];
  const float* W     = (const float*)d_in[2];
  const float* a_src = (const float*)d_in[3];
  const float* a_tgt = (const float*)d_in[4];
  const float* wres  = (const float*)d_in[5];
  float* out = (float*)d_out;
  float* wsf = (float*)d_ws;

  float*    proj    = wsf + OFF_PROJ;
  uint32_t* bitmask = (uint32_t*)(wsf + OFF_PROJ);   // overlays proj after k_sprep
  float*    resid   = wsf + OFF_RESID;
  uint32_t* packed  = (uint32_t*)(wsf + OFF_PACKED);
  float*    ss      = wsf + OFF_SS;
  float*    st      = wsf + OFF_ST;
  float*    csum    = wsf + OFF_CSUM;
  float*    stats   = wsf + OFF_STATS;
  float4*   ntab    = (float4*)(wsf + OFF_NTAB);
  float*    vals    = wsf + OFF_VALS;
  float*    wt      = wsf + OFF_WT;

  (void)hipMemsetAsync(csum, 0, (2 * NN + 16) * sizeof(float), stream);

  hipLaunchKernelGGL(k_wt,    dim3(DIN * FF / 256), dim3(256), 0, stream, wres, wt);
  hipLaunchKernelGGL(k_gemm,  dim3(NN / 64, 3),     dim3(256), 0, stream, x, W, wt, proj, resid);
  hipLaunchKernelGGL(k_sprep, dim3(NN / 4),         dim3(256), 0, stream, proj, a_src, a_tgt, ss, st, packed);
  hipLaunchKernelGGL(k_scan,  dim3(NN / 256, NN / 128), dim3(256), 0, stream, mask, out + NF, ss, st, csum, bitmask);
  hipLaunchKernelGGL(k_ntab,  dim3(NN / 256),       dim3(256), 0, stream, st, csum, ntab);
  hipLaunchKernelGGL(k_vals,  dim3(NN / 4),         dim3(256), 0, stream, bitmask, packed, ntab, ss, vals, stats);
  hipLaunchKernelGGL(k_final, dim3(NF / 1024),      dim3(256), 0, stream, vals, resid, stats, out);
}

// Round 8
// 852.422 us; speedup vs baseline: 1.0068x; 1.0068x over previous
//
#include <hip/hip_runtime.h>
#include <stdint.h>

#define NN   8192
#define DIN  256
#define FF   128
#define NF   (NN*FF)          // 1048576
#define SLOPE 0.2f
#define EPSI  1e-5f

typedef float vf4 __attribute__((ext_vector_type(4)));

#if __has_builtin(__builtin_amdgcn_sched_barrier)
#define SCHED_FENCE() __builtin_amdgcn_sched_barrier(0)
#else
#define SCHED_FENCE() asm volatile("" ::: "memory")
#endif

// ---- workspace layout (float offsets) ----
#define OFF_PROJ   0                       // [2][N][F] f32 (k_gemm->k_sprep), then REUSED as bitmask [N][256] u32 (8 MB)
#define OFF_RESID  (2*NF)                  // [N][F] f32
#define OFF_PACKED (3*NF)                  // [N][F] uint32: lo16=bf16(head0), hi16=bf16(head1)
#define OFF_SS     (4*NF)                  // s_src [2][N]
#define OFF_ST     (OFF_SS + 2*NN)         // s_tgt [2][N]
#define OFF_CSUM   (OFF_ST + 2*NN)         // colsum [2][N]
#define OFF_STATS  (OFF_CSUM + 2*NN)       // S, SS (2 floats; padded to 16)
#define OFF_NTAB   (OFF_STATS + 16)        // float4[N] = {st0, st1, rcp_csum0, rcp_csum1}
#define OFF_VALS   (OFF_NTAB + 4*NN)       // [N][F] f32
#define OFF_WT     (OFF_VALS + NF)         // W_res transposed: [DIN][F]

__device__ __forceinline__ float lrelu(float x) { return x >= 0.f ? x : SLOPE * x; }

__device__ __forceinline__ uint32_t bfpack(float a, float b) {
  uint32_t ua = __float_as_uint(a); ua += 0x7fffu + ((ua >> 16) & 1u);
  uint32_t ub = __float_as_uint(b); ub += 0x7fffu + ((ub >> 16) & 1u);
  return (ua >> 16) | (ub & 0xffff0000u);
}

// ---- K0: transpose W_res [F][DIN] -> Wt [DIN][F] ----
__global__ __launch_bounds__(256) void k_wt(const float* __restrict__ wres, float* __restrict__ wt) {
  int i = blockIdx.x * 256 + threadIdx.x;
  int d = i >> 7, f = i & 127;
  wt[i] = wres[f * DIN + d];
}

// ---- K1: 3 GEMMs M=8192 K=256 N=128 (heads 0,1 -> proj; y==2 -> resid) ----
__global__ __launch_bounds__(256) void k_gemm(const float* __restrict__ x, const float* __restrict__ Wh,
                                              const float* __restrict__ wt, float* __restrict__ proj,
                                              float* __restrict__ resid) {
  const int h = blockIdx.y;
  const float* __restrict__ Wsrc = (h < 2) ? (Wh + h * (DIN * FF)) : wt;
  float* __restrict__ outp = (h < 2) ? (proj + h * NF) : resid;
  const int row0 = blockIdx.x * 64;
  __shared__ float xs[64 * 68];
  const int tid = threadIdx.x;
  const int ft = tid & 15, rt = tid >> 4;
  const int f0 = ft * 8, r0 = rt * 4;
  float acc[4][8];
#pragma unroll
  for (int j = 0; j < 4; ++j)
#pragma unroll
    for (int k = 0; k < 8; ++k) acc[j][k] = 0.f;

  for (int kc = 0; kc < 4; ++kc) {
    const int d0 = kc * 64;
#pragma unroll
    for (int k2 = 0; k2 < 4; ++k2) {
      int i = tid * 4 + k2 * 1024;
      int r = i >> 6, dd = i & 63;
      *(float4*)&xs[r * 68 + dd] = *(const float4*)&x[(row0 + r) * DIN + d0 + dd];
    }
    __syncthreads();
#pragma unroll
    for (int g = 0; g < 16; ++g) {
      const int dd = g * 4;
      float xr[4][4];
#pragma unroll
      for (int j = 0; j < 4; ++j) {
        float4 t = *(const float4*)&xs[(r0 + j) * 68 + dd];
        xr[j][0] = t.x; xr[j][1] = t.y; xr[j][2] = t.z; xr[j][3] = t.w;
      }
#pragma unroll
      for (int i = 0; i < 4; ++i) {
        float4 wa = *(const float4*)&Wsrc[(d0 + dd + i) * FF + f0];
        float4 wb = *(const float4*)&Wsrc[(d0 + dd + i) * FF + f0 + 4];
#pragma unroll
        for (int j = 0; j < 4; ++j) {
          float xx = xr[j][i];
          acc[j][0] += xx * wa.x; acc[j][1] += xx * wa.y; acc[j][2] += xx * wa.z; acc[j][3] += xx * wa.w;
          acc[j][4] += xx * wb.x; acc[j][5] += xx * wb.y; acc[j][6] += xx * wb.z; acc[j][7] += xx * wb.w;
        }
      }
    }
    __syncthreads();
  }
#pragma unroll
  for (int j = 0; j < 4; ++j) {
    int row = row0 + r0 + j;
    *(float4*)&outp[row * FF + f0]     = make_float4(acc[j][0], acc[j][1], acc[j][2], acc[j][3]);
    *(float4*)&outp[row * FF + f0 + 4] = make_float4(acc[j][4], acc[j][5], acc[j][6], acc[j][7]);
  }
}

// ---- K1b: per-node dots s_src/s_tgt (both heads) + bf16 pack of proj ----
__global__ __launch_bounds__(256) void k_sprep(const float* __restrict__ proj, const float* __restrict__ a_src,
                                               const float* __restrict__ a_tgt, float* __restrict__ ss,
                                               float* __restrict__ st, uint32_t* __restrict__ packed) {
  int lane = threadIdx.x & 63, wid = threadIdx.x >> 6;
  int n = blockIdx.x * 4 + wid;
  float2 q0 = *(const float2*)&proj[n * FF + 2 * lane];
  float2 q1 = *(const float2*)&proj[NF + n * FF + 2 * lane];
  float2 as0 = *(const float2*)&a_src[2 * lane];
  float2 at0 = *(const float2*)&a_tgt[2 * lane];
  float2 as1 = *(const float2*)&a_src[FF + 2 * lane];
  float2 at1 = *(const float2*)&a_tgt[FF + 2 * lane];
  float v0 = q0.x * as0.x + q0.y * as0.y;
  float v1 = q0.x * at0.x + q0.y * at0.y;
  float v2 = q1.x * as1.x + q1.y * as1.y;
  float v3 = q1.x * at1.x + q1.y * at1.y;
#pragma unroll
  for (int o = 1; o < 64; o <<= 1) {
    v0 += __shfl_xor(v0, o); v1 += __shfl_xor(v1, o);
    v2 += __shfl_xor(v2, o); v3 += __shfl_xor(v3, o);
  }
  uint2 pk;
  pk.x = bfpack(q0.x, q1.x);
  pk.y = bfpack(q0.y, q1.y);
  *(uint2*)&packed[n * FF + 2 * lane] = pk;
  if (lane == 0) { ss[n] = v0; ss[NN + n] = v2; st[n] = v1; st[NN + n] = v3; }
}

// ---- K2 v6 (k_scan): float4 per thread; block = 1024 cols x 64 rows, grid (8,128).
// 8-row load batches (8 float4 in flight/thread); bitmask in r4-verified interleaved
// layout: word widx of row m: C=widx>>3, half=widx&1, j=(widx>>1)&3; bit b -> col
// C*256 + 128*half + 4*b + j. colsum in registers, 8 atomics/thread at the end. ----
__global__ __launch_bounds__(256) void k_scan(const float* __restrict__ mask, float* __restrict__ maskout,
                                              const float* __restrict__ ss, const float* __restrict__ st,
                                              float* __restrict__ csum, uint32_t* __restrict__ bitmask) {
  const int tid = threadIdx.x;
  const int lane = tid & 63, wv = tid >> 6;
  const int nb = blockIdx.x * 1024 + tid * 4;    // thread's first column
  const int C = blockIdx.x * 4 + wv;             // 256-col chunk id of this wave
  const int m0 = blockIdx.y * 64;
  const vf4 st0 = *(const vf4*)&st[nb];
  const vf4 st1 = *(const vf4*)&st[NN + nb];
  const float ssA = ss[m0 + lane];               // head0, rows m0..m0+63 across lanes
  const float ssC = ss[NN + m0 + lane];          // head1
  float c0[4] = {0.f, 0.f, 0.f, 0.f}, c1[4] = {0.f, 0.f, 0.f, 0.f};

  for (int i = 0; i < 64; i += 8) {
    vf4 v[8];
#pragma unroll
    for (int r = 0; r < 8; ++r)
      v[r] = *(const vf4*)&mask[(size_t)(m0 + i + r) * NN + nb];
#pragma unroll
    for (int r = 0; r < 8; ++r) {
      const int m = m0 + i + r;
      __builtin_nontemporal_store(v[r], (vf4*)&maskout[(size_t)m * NN + nb]);
      unsigned long long bms[4];
      bool e[4];
#pragma unroll
      for (int j = 0; j < 4; ++j) { e[j] = v[r][j] > -0.5e9f; bms[j] = __ballot(e[j]); }
      if (lane < 8)
        bitmask[m * 256 + C * 8 + lane] = (uint32_t)(bms[lane >> 1] >> ((lane & 1) * 32));
      const int ri = i + r;                      // uniform row index in [0,64)
      float s0 = __uint_as_float(__builtin_amdgcn_readlane(__float_as_uint(ssA), ri));
      float s1 = __uint_as_float(__builtin_amdgcn_readlane(__float_as_uint(ssC), ri));
#pragma unroll
      for (int j = 0; j < 4; ++j) {
        float w0 = __expf(lrelu(s0 + st0[j]));
        float w1 = __expf(lrelu(s1 + st1[j]));
        c0[j] += e[j] ? w0 : 0.f;
        c1[j] += e[j] ? w1 : 0.f;
      }
    }
  }
#pragma unroll
  for (int j = 0; j < 4; ++j) {
    atomicAdd(&csum[nb + j], c0[j]);
    atomicAdd(&csum[NN + nb + j], c1[j]);
  }
}

// ---- K2c: pack per-column table {st0, st1, 1/csum0, 1/csum1} ----
__global__ __launch_bounds__(256) void k_ntab(const float* __restrict__ st, const float* __restrict__ csum,
                                              float4* __restrict__ ntab) {
  int i = blockIdx.x * 256 + threadIdx.x;
  ntab[i] = make_float4(st[i], st[NN + i], 1.f / csum[i], 1.f / csum[NN + i]);
}

// ---- K3 v7: wave-per-row. Phase 1: decode interleaved bitmask -> LDS edge list
// (r4-verified mapping). Phase 2: 64-edge tiles; 16-edge register batches with a
// sched_barrier between loads and consumes -> d[16] forced live -> 16 loads in
// flight per wave (vmcnt pipelining), full occupancy (8 KB LDS, ~70 VGPR). ----
__global__ __launch_bounds__(256) void k_vals(const uint32_t* __restrict__ bitmask, const uint32_t* __restrict__ packed,
                                              const float4* __restrict__ ntab, const float* __restrict__ ss,
                                              float* __restrict__ vals, float* __restrict__ stats) {
  __shared__ uint16_t el[4][1024];
  const int lane = threadIdx.x & 63, wid = threadIdx.x >> 6;
  const int m = blockIdx.x * 4 + wid;

  // ---- phase 1: decode bitmask row m ----
  uint4 wv = ((const uint4*)(bitmask + m * 256))[lane];   // words 4*lane..4*lane+3
  uint32_t wd[4] = {wv.x, wv.y, wv.z, wv.w};
  int cnt = __popc(wd[0]) + __popc(wd[1]) + __popc(wd[2]) + __popc(wd[3]);
  int pre = cnt;
#pragma unroll
  for (int o = 1; o < 64; o <<= 1) { int t = __shfl_up(pre, o); if (lane >= o) pre += t; }
  int nE = __shfl(pre, 63);
  int base = pre - cnt;
#pragma unroll
  for (int u = 0; u < 4; ++u) {
    uint32_t w = wd[u];
    int widx = 4 * lane + u;
    int nbase = (widx >> 3) * 256 + (widx & 1) * 128 + ((widx >> 1) & 3);
    while (w) {
      int b = __builtin_ctz(w); w &= w - 1;
      if (base < 1024) el[wid][base] = (uint16_t)(nbase + 4 * b);
      ++base;
    }
  }
  if (nE > 1024) nE = 1024;
  __builtin_amdgcn_wave_barrier();

  // ---- phase 2: tiled gather, 16-deep register batches fenced by sched_barrier ----
  const float ss0 = ss[m], ss1 = ss[NN + m];
  float a00 = 0.f, a01 = 0.f, a10 = 0.f, a11 = 0.f;   // f=2*lane, f=2*lane+1 (h0,h1 each)
  const char* __restrict__ pb = (const char*)packed;
  const int lane8 = 8 * lane;
  for (int t = 0; t < nE; t += 64) {
    int e = t + lane;
    float w0 = 0.f, w1 = 0.f; uint32_t off = 0;
    if (e < nE) {
      int n = el[wid][e];
      float4 tb = ntab[n];
      w0 = __expf(lrelu(ss0 + tb.x)) * tb.z;
      w1 = __expf(lrelu(ss1 + tb.y)) * tb.w;
      off = (uint32_t)n << 9;
    }
#pragma unroll 1
    for (int k2 = 0; k2 < 4; ++k2) {
      uint2 d[16];
      const int kb = k2 * 16;
#pragma unroll
      for (int j = 0; j < 16; ++j) {
        uint32_t so = __builtin_amdgcn_readlane(off, kb + j);
        d[j] = *(const uint2*)(pb + so + lane8);
      }
      SCHED_FENCE();      // loads above, consumes below: d[16] live -> 16 in flight
#pragma unroll
      for (int j = 0; j < 16; ++j) {
        float sw0 = __uint_as_float(__builtin_amdgcn_readlane(__float_as_uint(w0), kb + j));
        float sw1 = __uint_as_float(__builtin_amdgcn_readlane(__float_as_uint(w1), kb + j));
        uint32_t pa = d[j].x, pc = d[j].y;
        a00 += sw0 * __uint_as_float(pa << 16);
        a10 += sw1 * __uint_as_float(pa & 0xffff0000u);
        a01 += sw0 * __uint_as_float(pc << 16);
        a11 += sw1 * __uint_as_float(pc & 0xffff0000u);
      }
    }
  }

  float v0 = 0.5f * (a00 + a10), v1 = 0.5f * (a01 + a11);
  *(float2*)&vals[m * FF + 2 * lane] = make_float2(v0, v1);
  float s = v0 + v1, q = v0 * v0 + v1 * v1;
#pragma unroll
  for (int o = 1; o < 64; o <<= 1) { s += __shfl_xor(s, o); q += __shfl_xor(q, o); }
  if (lane == 0) { atomicAdd(stats, s); atomicAdd(stats + 1, q); }
}

// ---- K5: instance-norm + residual + ELU ----
__global__ __launch_bounds__(256) void k_final(const float* __restrict__ vals, const float* __restrict__ resid,
                                               const float* __restrict__ stats, float* __restrict__ out) {
  int i = (blockIdx.x * 256 + threadIdx.x) * 4;
  float mu = stats[0] * (1.f / NF);
  float var = stats[1] * (1.f / NF) - mu * mu;
  float rs = rsqrtf(var + EPSI);
  float4 v = *(const float4*)&vals[i];
  float4 r = *(const float4*)&resid[i];
  float t0 = (v.x - mu) * rs + r.x;
  float t1 = (v.y - mu) * rs + r.y;
  float t2 = (v.z - mu) * rs + r.z;
  float t3 = (v.w - mu) * rs + r.w;
  float4 o;
  o.x = t0 > 0.f ? t0 : expm1f(t0);
  o.y = t1 > 0.f ? t1 : expm1f(t1);
  o.z = t2 > 0.f ? t2 : expm1f(t2);
  o.w = t3 > 0.f ? t3 : expm1f(t3);
  *(float4*)&out[i] = o;
}

extern "C" void kernel_launch(void* const* d_in, const int* in_sizes, int n_in,
                              void* d_out, int out_size, void* d_ws, size_t ws_size,
                              hipStream_t stream) {
  const float* x     = (const float*)d_in[0];
  const float* mask  = (const float*)d_in[1];
  const float* W     = (const float*)d_in[2];
  const float* a_src = (const float*)d_in[3];
  const float* a_tgt = (const float*)d_in[4];
  const float* wres  = (const float*)d_in[5];
  float* out = (float*)d_out;
  float* wsf = (float*)d_ws;

  float*    proj    = wsf + OFF_PROJ;
  uint32_t* bitmask = (uint32_t*)(wsf + OFF_PROJ);   // overlays proj after k_sprep
  float*    resid   = wsf + OFF_RESID;
  uint32_t* packed  = (uint32_t*)(wsf + OFF_PACKED);
  float*    ss      = wsf + OFF_SS;
  float*    st      = wsf + OFF_ST;
  float*    csum    = wsf + OFF_CSUM;
  float*    stats   = wsf + OFF_STATS;
  float4*   ntab    = (float4*)(wsf + OFF_NTAB);
  float*    vals    = wsf + OFF_VALS;
  float*    wt      = wsf + OFF_WT;

  (void)hipMemsetAsync(csum, 0, (2 * NN + 16) * sizeof(float), stream);

  hipLaunchKernelGGL(k_wt,    dim3(DIN * FF / 256), dim3(256), 0, stream, wres, wt);
  hipLaunchKernelGGL(k_gemm,  dim3(NN / 64, 3),     dim3(256), 0, stream, x, W, wt, proj, resid);
  hipLaunchKernelGGL(k_sprep, dim3(NN / 4),         dim3(256), 0, stream, proj, a_src, a_tgt, ss, st, packed);
  hipLaunchKernelGGL(k_scan,  dim3(NN / 1024, NN / 64), dim3(256), 0, stream, mask, out + NF, ss, st, csum, bitmask);
  hipLaunchKernelGGL(k_ntab,  dim3(NN / 256),       dim3(256), 0, stream, st, csum, ntab);
  hipLaunchKernelGGL(k_vals,  dim3(NN / 4),         dim3(256), 0, stream, bitmask, packed, ntab, ss, vals, stats);
  hipLaunchKernelGGL(k_final, dim3(NF / 1024),      dim3(256), 0, stream, vals, resid, stats, out);
}

// Round 9
// 840.024 us; speedup vs baseline: 1.0216x; 1.0148x over previous
//
#include <hip/hip_runtime.h>
#include <stdint.h>

#define NN   8192
#define DIN  256
#define FF   128
#define NF   (NN*FF)          // 1048576
#define SLOPE 0.2f
#define EPSI  1e-5f

typedef float vf4 __attribute__((ext_vector_type(4)));
typedef short bf16x8 __attribute__((ext_vector_type(8)));
typedef float f32x4 __attribute__((ext_vector_type(4)));

// ---- workspace layout (float offsets) ----
#define OFF_PROJ   0                       // [2][N][F] f32 (k_gemm->k_sprep), then REUSED as bitmask [N][256] u32 (8 MB)
#define OFF_RESID  (2*NF)                  // [N][F] f32
#define OFF_PACKED (3*NF)                  // [N][F] u32: lo16=bf16(h0), hi16=bf16(h1)
#define OFF_SS     (4*NF)                  // s_src [2][N]
#define OFF_ST     (OFF_SS + 2*NN)         // s_tgt [2][N]
#define OFF_CSUM   (OFF_ST + 2*NN)         // colsum [2][N]
#define OFF_STATS  (OFF_CSUM + 2*NN)       // S, SS (padded to 16)
#define OFF_NTAB   (OFF_STATS + 16)        // float4[N] = {st0, st1, rcp0, rcp1}
#define OFF_VALS   (OFF_NTAB + 4*NN)       // [N][F] f32
#define OFF_WT     (OFF_VALS + NF)         // W_res^T [DIN][F]
#define OFF_PT2    (OFF_WT + DIN*FF)       // packedT2: [N/32][2][128][16] u32 (4 MB)

__device__ __forceinline__ float lrelu(float x) { return x >= 0.f ? x : SLOPE * x; }

__device__ __forceinline__ uint32_t bfpack(float a, float b) {
  uint32_t ua = __float_as_uint(a); ua += 0x7fffu + ((ua >> 16) & 1u);
  uint32_t ub = __float_as_uint(b); ub += 0x7fffu + ((ub >> 16) & 1u);
  return (ua >> 16) | (ub & 0xffff0000u);
}

// ---- K0: transpose W_res [F][DIN] -> Wt [DIN][F] ----
__global__ __launch_bounds__(256) void k_wt(const float* __restrict__ wres, float* __restrict__ wt) {
  int i = blockIdx.x * 256 + threadIdx.x;
  int d = i >> 7, f = i & 127;
  wt[i] = wres[f * DIN + d];
}

// ---- K1: 3 GEMMs M=8192 K=256 N=128 (heads 0,1 -> proj; y==2 -> resid) ----
__global__ __launch_bounds__(256) void k_gemm(const float* __restrict__ x, const float* __restrict__ Wh,
                                              const float* __restrict__ wt, float* __restrict__ proj,
                                              float* __restrict__ resid) {
  const int h = blockIdx.y;
  const float* __restrict__ Wsrc = (h < 2) ? (Wh + h * (DIN * FF)) : wt;
  float* __restrict__ outp = (h < 2) ? (proj + h * NF) : resid;
  const int row0 = blockIdx.x * 64;
  __shared__ float xs[64 * 68];
  const int tid = threadIdx.x;
  const int ft = tid & 15, rt = tid >> 4;
  const int f0 = ft * 8, r0 = rt * 4;
  float acc[4][8];
#pragma unroll
  for (int j = 0; j < 4; ++j)
#pragma unroll
    for (int k = 0; k < 8; ++k) acc[j][k] = 0.f;

  for (int kc = 0; kc < 4; ++kc) {
    const int d0 = kc * 64;
#pragma unroll
    for (int k2 = 0; k2 < 4; ++k2) {
      int i = tid * 4 + k2 * 1024;
      int r = i >> 6, dd = i & 63;
      *(float4*)&xs[r * 68 + dd] = *(const float4*)&x[(row0 + r) * DIN + d0 + dd];
    }
    __syncthreads();
#pragma unroll
    for (int g = 0; g < 16; ++g) {
      const int dd = g * 4;
      float xr[4][4];
#pragma unroll
      for (int j = 0; j < 4; ++j) {
        float4 t = *(const float4*)&xs[(r0 + j) * 68 + dd];
        xr[j][0] = t.x; xr[j][1] = t.y; xr[j][2] = t.z; xr[j][3] = t.w;
      }
#pragma unroll
      for (int i = 0; i < 4; ++i) {
        float4 wa = *(const float4*)&Wsrc[(d0 + dd + i) * FF + f0];
        float4 wb = *(const float4*)&Wsrc[(d0 + dd + i) * FF + f0 + 4];
#pragma unroll
        for (int j = 0; j < 4; ++j) {
          float xx = xr[j][i];
          acc[j][0] += xx * wa.x; acc[j][1] += xx * wa.y; acc[j][2] += xx * wa.z; acc[j][3] += xx * wa.w;
          acc[j][4] += xx * wb.x; acc[j][5] += xx * wb.y; acc[j][6] += xx * wb.z; acc[j][7] += xx * wb.w;
        }
      }
    }
    __syncthreads();
  }
#pragma unroll
  for (int j = 0; j < 4; ++j) {
    int row = row0 + r0 + j;
    *(float4*)&outp[row * FF + f0]     = make_float4(acc[j][0], acc[j][1], acc[j][2], acc[j][3]);
    *(float4*)&outp[row * FF + f0 + 4] = make_float4(acc[j][4], acc[j][5], acc[j][6], acc[j][7]);
  }
}

// ---- K1b: per-node dots s_src/s_tgt (both heads) + bf16 pack of proj ----
__global__ __launch_bounds__(256) void k_sprep(const float* __restrict__ proj, const float* __restrict__ a_src,
                                               const float* __restrict__ a_tgt, float* __restrict__ ss,
                                               float* __restrict__ st, uint32_t* __restrict__ packed) {
  int lane = threadIdx.x & 63, wid = threadIdx.x >> 6;
  int n = blockIdx.x * 4 + wid;
  float2 q0 = *(const float2*)&proj[n * FF + 2 * lane];
  float2 q1 = *(const float2*)&proj[NF + n * FF + 2 * lane];
  float2 as0 = *(const float2*)&a_src[2 * lane];
  float2 at0 = *(const float2*)&a_tgt[2 * lane];
  float2 as1 = *(const float2*)&a_src[FF + 2 * lane];
  float2 at1 = *(const float2*)&a_tgt[FF + 2 * lane];
  float v0 = q0.x * as0.x + q0.y * as0.y;
  float v1 = q0.x * at0.x + q0.y * at0.y;
  float v2 = q1.x * as1.x + q1.y * as1.y;
  float v3 = q1.x * at1.x + q1.y * at1.y;
#pragma unroll
  for (int o = 1; o < 64; o <<= 1) {
    v0 += __shfl_xor(v0, o); v1 += __shfl_xor(v1, o);
    v2 += __shfl_xor(v2, o); v3 += __shfl_xor(v3, o);
  }
  uint2 pk;
  pk.x = bfpack(q0.x, q1.x);
  pk.y = bfpack(q0.y, q1.y);
  *(uint2*)&packed[n * FF + 2 * lane] = pk;
  if (lane == 0) { ss[n] = v0; ss[NN + n] = v2; st[n] = v1; st[NN + n] = v3; }
}

// ---- K1c: packed[n][f] -> packedT2[n/32][h][f][n&31] bf16-pair words ----
__global__ __launch_bounds__(256) void k_tpose(const uint32_t* __restrict__ packed, uint32_t* __restrict__ pt2) {
  __shared__ uint32_t sb[32][129];
  const int t = threadIdx.x, c = blockIdx.x;
  const int nl = t >> 3, fb = (t & 7) * 16;
#pragma unroll
  for (int i = 0; i < 4; ++i) {
    uint4 v = *(const uint4*)&packed[(c * 32 + nl) * FF + fb + i * 4];
    sb[nl][fb + i * 4] = v.x; sb[nl][fb + i * 4 + 1] = v.y;
    sb[nl][fb + i * 4 + 2] = v.z; sb[nl][fb + i * 4 + 3] = v.w;
  }
  __syncthreads();
  const int h = t >> 7, f = t & 127;
  uint32_t wbuf[16];
#pragma unroll
  for (int p = 0; p < 16; ++p) {
    uint32_t a = sb[2 * p][f], b = sb[2 * p + 1][f];
    wbuf[p] = h ? ((a >> 16) | (b & 0xffff0000u)) : ((a & 0xffffu) | (b << 16));
  }
  uint32_t* dst = pt2 + ((c * 2 + h) * 128 + f) * 16;
#pragma unroll
  for (int i = 0; i < 4; ++i)
    *(uint4*)&dst[i * 4] = make_uint4(wbuf[i * 4], wbuf[i * 4 + 1], wbuf[i * 4 + 2], wbuf[i * 4 + 3]);
}

// ---- K2 (k_scan, r7-verified): copy mask -> out1, emit SORTED bitmask
// (word = m*256 + n/32, bit = n&31), colsum in registers + 2 atomics/thread. ----
__global__ __launch_bounds__(256) void k_scan(const float* __restrict__ mask, float* __restrict__ maskout,
                                              const float* __restrict__ ss, const float* __restrict__ st,
                                              float* __restrict__ csum, uint32_t* __restrict__ bitmask) {
  const int tid = threadIdx.x;
  const int lane = tid & 63, wv = tid >> 6;
  const int n = blockIdx.x * 256 + tid;
  const int m0 = blockIdx.y * 128;
  const int wbase = blockIdx.x * 8 + wv * 2;
  const float st0 = st[n], st1 = st[NN + n];
  const float ssA = ss[m0 + lane],      ssB = ss[m0 + 64 + lane];
  const float ssC = ss[NN + m0 + lane], ssD = ss[NN + m0 + 64 + lane];
  float c0 = 0.f, c1 = 0.f;

  for (int i = 0; i < 128; i += 8) {
    float v[8];
#pragma unroll
    for (int r = 0; r < 8; ++r)
      v[r] = __builtin_nontemporal_load(&mask[(size_t)(m0 + i + r) * NN + n]);
#pragma unroll
    for (int r = 0; r < 8; ++r) {
      const int m = m0 + i + r;
      __builtin_nontemporal_store(v[r], &maskout[(size_t)m * NN + n]);
      bool e = v[r] > -0.5e9f;
      unsigned long long bm = __ballot(e);
      if (lane == 0)
        *(uint2*)&bitmask[m * 256 + wbase] = make_uint2((uint32_t)bm, (uint32_t)(bm >> 32));
      const int ri = i + r;
      float s0 = __uint_as_float(__builtin_amdgcn_readlane(
                   __float_as_uint(ri < 64 ? ssA : ssB), ri & 63));
      float s1 = __uint_as_float(__builtin_amdgcn_readlane(
                   __float_as_uint(ri < 64 ? ssC : ssD), ri & 63));
      float w0 = __expf(lrelu(s0 + st0));
      float w1 = __expf(lrelu(s1 + st1));
      c0 += e ? w0 : 0.f;
      c1 += e ? w1 : 0.f;
    }
  }
  atomicAdd(&csum[n], c0);
  atomicAdd(&csum[NN + n], c1);
}

// ---- K2c: pack per-column table {st0, st1, 1/csum0, 1/csum1} ----
__global__ __launch_bounds__(256) void k_ntab(const float* __restrict__ st, const float* __restrict__ csum,
                                              float4* __restrict__ ntab) {
  int i = blockIdx.x * 256 + threadIdx.x;
  ntab[i] = make_float4(st[i], st[NN + i], 1.f / csum[i], 1.f / csum[NN + i]);
}

// ---- K3 v8: DENSE MFMA. Block = 128 thr (2 waves) = 32 m-rows, full n-range.
// Per 32-n step: stage proj chunk (16 KB, contiguous from packedT2) into lds_B;
// build A = w[m,n] bf16 (bit ? exp(lrelu(ss+st))*rcp : 0) into lds_A; 2 waves
// each do 16m x 128f via 16x16x32 bf16 MFMA, K folded over {h0,h1} x 32 n. ----
__global__ __launch_bounds__(128) void k_vals(const uint32_t* __restrict__ bitmask, const uint32_t* __restrict__ pt2,
                                              const float4* __restrict__ ntab, const float* __restrict__ ss,
                                              float* __restrict__ vals, float* __restrict__ stats) {
  __shared__ short lds_B[2][128][40];   // [h][f][n] bf16, padded row 40
  __shared__ short lds_A[2][32][40];    // [h][m][n] bf16, padded row 40
  const int t = threadIdx.x;
  const int lane = t & 63, wid = t >> 6;
  const int m0 = blockIdx.x * 32;
  const int q = lane >> 4, col = lane & 15;
  const int n2 = t & 15, mg = t >> 4;          // A-build mapping: n-pair, m-subgroup(0..7)

  // preload ss for this thread's 4 m-rows (both heads)
  float ssm0[4], ssm1[4];
#pragma unroll
  for (int p = 0; p < 4; ++p) {
    ssm0[p] = ss[m0 + mg + 8 * p];
    ssm1[p] = ss[NN + m0 + mg + 8 * p];
  }

  f32x4 acc[8];
#pragma unroll
  for (int i = 0; i < 8; ++i) acc[i] = (f32x4){0.f, 0.f, 0.f, 0.f};

  uint32_t* ldsb_w = (uint32_t*)&lds_B[0][0][0];

  for (int step = 0; step < NN / 32; ++step) {
    const int n0 = step * 32;
    // ---- stage B: 4096 words contiguous -> padded LDS rows (row=20 dwords) ----
    const uint32_t* src = pt2 + step * 4096;
#pragma unroll
    for (int i = 0; i < 8; ++i) {
      uint4 v = *(const uint4*)&src[t * 4 + i * 512];
      int row = (t >> 2) + i * 32, c4 = (t & 3) * 4;
      *(uint4*)&ldsb_w[row * 20 + c4] = v;
    }
    // ---- build A: 32m x 32n x 2h ----
    float4 na = ntab[n0 + 2 * n2];
    float4 nb = ntab[n0 + 2 * n2 + 1];
#pragma unroll
    for (int p = 0; p < 4; ++p) {
      const int ml = mg + 8 * p;
      uint32_t bw = bitmask[(size_t)(m0 + ml) * 256 + (n0 >> 5)];
      float e0a = __expf(lrelu(ssm0[p] + na.x)) * na.z;
      float e1a = __expf(lrelu(ssm1[p] + na.y)) * na.w;
      float e0b = __expf(lrelu(ssm0[p] + nb.x)) * nb.z;
      float e1b = __expf(lrelu(ssm1[p] + nb.y)) * nb.w;
      bool b0 = (bw >> (2 * n2)) & 1, b1 = (bw >> (2 * n2 + 1)) & 1;
      e0a = b0 ? e0a : 0.f; e1a = b0 ? e1a : 0.f;
      e0b = b1 ? e0b : 0.f; e1b = b1 ? e1b : 0.f;
      *(uint32_t*)&lds_A[0][ml][2 * n2] = bfpack(e0a, e0b);
      *(uint32_t*)&lds_A[1][ml][2 * n2] = bfpack(e1a, e1b);
    }
    __syncthreads();
    // ---- MFMA: wave wid covers m-rows m0+wid*16..+15, all 128 f ----
    bf16x8 a0 = *(const bf16x8*)&lds_A[0][wid * 16 + col][q * 8];
    bf16x8 a1 = *(const bf16x8*)&lds_A[1][wid * 16 + col][q * 8];
#pragma unroll
    for (int ft = 0; ft < 8; ++ft) {
      bf16x8 b0 = *(const bf16x8*)&lds_B[0][ft * 16 + col][q * 8];
      acc[ft] = __builtin_amdgcn_mfma_f32_16x16x32_bf16(a0, b0, acc[ft], 0, 0, 0);
      bf16x8 b1 = *(const bf16x8*)&lds_B[1][ft * 16 + col][q * 8];
      acc[ft] = __builtin_amdgcn_mfma_f32_16x16x32_bf16(a1, b1, acc[ft], 0, 0, 0);
    }
    __syncthreads();
  }

  // ---- store vals (head mean = x0.5) + stats ----
  float s = 0.f, qq = 0.f;
#pragma unroll
  for (int ft = 0; ft < 8; ++ft) {
#pragma unroll
    for (int r = 0; r < 4; ++r) {
      int mrow = m0 + wid * 16 + q * 4 + r;
      float v = 0.5f * acc[ft][r];
      vals[mrow * FF + ft * 16 + col] = v;
      s += v; qq += v * v;
    }
  }
#pragma unroll
  for (int o = 1; o < 64; o <<= 1) { s += __shfl_xor(s, o); qq += __shfl_xor(qq, o); }
  if (lane == 0) { atomicAdd(stats, s); atomicAdd(stats + 1, qq); }
}

// ---- K5: instance-norm + residual + ELU ----
__global__ __launch_bounds__(256) void k_final(const float* __restrict__ vals, const float* __restrict__ resid,
                                               const float* __restrict__ stats, float* __restrict__ out) {
  int i = (blockIdx.x * 256 + threadIdx.x) * 4;
  float mu = stats[0] * (1.f / NF);
  float var = stats[1] * (1.f / NF) - mu * mu;
  float rs = rsqrtf(var + EPSI);
  float4 v = *(const float4*)&vals[i];
  float4 r = *(const float4*)&resid[i];
  float t0 = (v.x - mu) * rs + r.x;
  float t1 = (v.y - mu) * rs + r.y;
  float t2 = (v.z - mu) * rs + r.z;
  float t3 = (v.w - mu) * rs + r.w;
  float4 o;
  o.x = t0 > 0.f ? t0 : expm1f(t0);
  o.y = t1 > 0.f ? t1 : expm1f(t1);
  o.z = t2 > 0.f ? t2 : expm1f(t2);
  o.w = t3 > 0.f ? t3 : expm1f(t3);
  *(float4*)&out[i] = o;
}

extern "C" void kernel_launch(void* const* d_in, const int* in_sizes, int n_in,
                              void* d_out, int out_size, void* d_ws, size_t ws_size,
                              hipStream_t stream) {
  const float* x     = (const float*)d_in[0];
  const float* mask  = (const float*)d_in[1];
  const float* W     = (const float*)d_in[2];
  const float* a_src = (const float*)d_in[3];
  const float* a_tgt = (const float*)d_in[4];
  const float* wres  = (const float*)d_in[5];
  float* out = (float*)d_out;
  float* wsf = (float*)d_ws;

  float*    proj    = wsf + OFF_PROJ;
  uint32_t* bitmask = (uint32_t*)(wsf + OFF_PROJ);   // overlays proj after k_sprep
  float*    resid   = wsf + OFF_RESID;
  uint32_t* packed  = (uint32_t*)(wsf + OFF_PACKED);
  float*    ss      = wsf + OFF_SS;
  float*    st      = wsf + OFF_ST;
  float*    csum    = wsf + OFF_CSUM;
  float*    stats   = wsf + OFF_STATS;
  float4*   ntab    = (float4*)(wsf + OFF_NTAB);
  float*    vals    = wsf + OFF_VALS;
  float*    wt      = wsf + OFF_WT;
  uint32_t* pt2     = (uint32_t*)(wsf + OFF_PT2);

  (void)hipMemsetAsync(csum, 0, (2 * NN + 16) * sizeof(float), stream);

  hipLaunchKernelGGL(k_wt,    dim3(DIN * FF / 256), dim3(256), 0, stream, wres, wt);
  hipLaunchKernelGGL(k_gemm,  dim3(NN / 64, 3),     dim3(256), 0, stream, x, W, wt, proj, resid);
  hipLaunchKernelGGL(k_sprep, dim3(NN / 4),         dim3(256), 0, stream, proj, a_src, a_tgt, ss, st, packed);
  hipLaunchKernelGGL(k_tpose, dim3(NN / 32),        dim3(256), 0, stream, packed, pt2);
  hipLaunchKernelGGL(k_scan,  dim3(NN / 256, NN / 128), dim3(256), 0, stream, mask, out + NF, ss, st, csum, bitmask);
  hipLaunchKernelGGL(k_ntab,  dim3(NN / 256),       dim3(256), 0, stream, st, csum, ntab);
  hipLaunchKernelGGL(k_vals,  dim3(NN / 32),        dim3(128), 0, stream, bitmask, pt2, ntab, ss, vals, stats);
  hipLaunchKernelGGL(k_final, dim3(NF / 1024),      dim3(256), 0, stream, vals, resid, stats, out);
}

// Round 10
// 732.512 us; speedup vs baseline: 1.1716x; 1.1468x over previous
//
#include <hip/hip_runtime.h>
#include <stdint.h>

#define NN   8192
#define DIN  256
#define FF   128
#define NF   (NN*FF)          // 1048576
#define SLOPE 0.2f
#define EPSI  1e-5f

typedef float vf4 __attribute__((ext_vector_type(4)));
typedef short bf16x8 __attribute__((ext_vector_type(8)));
typedef float f32x4 __attribute__((ext_vector_type(4)));

// ---- workspace layout (float offsets) ----
#define OFF_PROJ   0                       // [2][N][F] f32 (k_gemm->k_sprep), then REUSED as bitmask [N][256] u32 (8 MB)
#define OFF_RESID  (2*NF)                  // [N][F] f32
#define OFF_PACKED (3*NF)                  // [N][F] u32: lo16=bf16(h0), hi16=bf16(h1)
#define OFF_SS     (4*NF)                  // s_src [2][N]
#define OFF_ST     (OFF_SS + 2*NN)         // s_tgt [2][N]
#define OFF_CSUM   (OFF_ST + 2*NN)         // colsum [2][N]
#define OFF_STATS  (OFF_CSUM + 2*NN)       // S, SS (padded to 16)
#define OFF_NTAB   (OFF_STATS + 16)        // float4[N] = {st0, st1, rcp0, rcp1}
#define OFF_VALS   (OFF_NTAB + 4*NN)       // [N][F] f32
#define OFF_WT     (OFF_VALS + NF)         // W_res^T [DIN][F]
#define OFF_PT2    (OFF_WT + DIN*FF)       // packedT2: [N/32][2][128][16] u32 (4 MB)

__device__ __forceinline__ float lrelu(float x) { return x >= 0.f ? x : SLOPE * x; }

__device__ __forceinline__ uint32_t bfpack(float a, float b) {
  uint32_t ua = __float_as_uint(a); ua += 0x7fffu + ((ua >> 16) & 1u);
  uint32_t ub = __float_as_uint(b); ub += 0x7fffu + ((ub >> 16) & 1u);
  return (ua >> 16) | (ub & 0xffff0000u);
}

// ---- K0: transpose W_res [F][DIN] -> Wt [DIN][F] ----
__global__ __launch_bounds__(256) void k_wt(const float* __restrict__ wres, float* __restrict__ wt) {
  int i = blockIdx.x * 256 + threadIdx.x;
  int d = i >> 7, f = i & 127;
  wt[i] = wres[f * DIN + d];
}

// ---- K1: 3 GEMMs M=8192 K=256 N=128 (heads 0,1 -> proj; y==2 -> resid) ----
__global__ __launch_bounds__(256) void k_gemm(const float* __restrict__ x, const float* __restrict__ Wh,
                                              const float* __restrict__ wt, float* __restrict__ proj,
                                              float* __restrict__ resid) {
  const int h = blockIdx.y;
  const float* __restrict__ Wsrc = (h < 2) ? (Wh + h * (DIN * FF)) : wt;
  float* __restrict__ outp = (h < 2) ? (proj + h * NF) : resid;
  const int row0 = blockIdx.x * 64;
  __shared__ float xs[64 * 68];
  const int tid = threadIdx.x;
  const int ft = tid & 15, rt = tid >> 4;
  const int f0 = ft * 8, r0 = rt * 4;
  float acc[4][8];
#pragma unroll
  for (int j = 0; j < 4; ++j)
#pragma unroll
    for (int k = 0; k < 8; ++k) acc[j][k] = 0.f;

  for (int kc = 0; kc < 4; ++kc) {
    const int d0 = kc * 64;
#pragma unroll
    for (int k2 = 0; k2 < 4; ++k2) {
      int i = tid * 4 + k2 * 1024;
      int r = i >> 6, dd = i & 63;
      *(float4*)&xs[r * 68 + dd] = *(const float4*)&x[(row0 + r) * DIN + d0 + dd];
    }
    __syncthreads();
#pragma unroll
    for (int g = 0; g < 16; ++g) {
      const int dd = g * 4;
      float xr[4][4];
#pragma unroll
      for (int j = 0; j < 4; ++j) {
        float4 t = *(const float4*)&xs[(r0 + j) * 68 + dd];
        xr[j][0] = t.x; xr[j][1] = t.y; xr[j][2] = t.z; xr[j][3] = t.w;
      }
#pragma unroll
      for (int i = 0; i < 4; ++i) {
        float4 wa = *(const float4*)&Wsrc[(d0 + dd + i) * FF + f0];
        float4 wb = *(const float4*)&Wsrc[(d0 + dd + i) * FF + f0 + 4];
#pragma unroll
        for (int j = 0; j < 4; ++j) {
          float xx = xr[j][i];
          acc[j][0] += xx * wa.x; acc[j][1] += xx * wa.y; acc[j][2] += xx * wa.z; acc[j][3] += xx * wa.w;
          acc[j][4] += xx * wb.x; acc[j][5] += xx * wb.y; acc[j][6] += xx * wb.z; acc[j][7] += xx * wb.w;
        }
      }
    }
    __syncthreads();
  }
#pragma unroll
  for (int j = 0; j < 4; ++j) {
    int row = row0 + r0 + j;
    *(float4*)&outp[row * FF + f0]     = make_float4(acc[j][0], acc[j][1], acc[j][2], acc[j][3]);
    *(float4*)&outp[row * FF + f0 + 4] = make_float4(acc[j][4], acc[j][5], acc[j][6], acc[j][7]);
  }
}

// ---- K1b: per-node dots s_src/s_tgt (both heads) + bf16 pack of proj ----
__global__ __launch_bounds__(256) void k_sprep(const float* __restrict__ proj, const float* __restrict__ a_src,
                                               const float* __restrict__ a_tgt, float* __restrict__ ss,
                                               float* __restrict__ st, uint32_t* __restrict__ packed) {
  int lane = threadIdx.x & 63, wid = threadIdx.x >> 6;
  int n = blockIdx.x * 4 + wid;
  float2 q0 = *(const float2*)&proj[n * FF + 2 * lane];
  float2 q1 = *(const float2*)&proj[NF + n * FF + 2 * lane];
  float2 as0 = *(const float2*)&a_src[2 * lane];
  float2 at0 = *(const float2*)&a_tgt[2 * lane];
  float2 as1 = *(const float2*)&a_src[FF + 2 * lane];
  float2 at1 = *(const float2*)&a_tgt[FF + 2 * lane];
  float v0 = q0.x * as0.x + q0.y * as0.y;
  float v1 = q0.x * at0.x + q0.y * at0.y;
  float v2 = q1.x * as1.x + q1.y * as1.y;
  float v3 = q1.x * at1.x + q1.y * at1.y;
#pragma unroll
  for (int o = 1; o < 64; o <<= 1) {
    v0 += __shfl_xor(v0, o); v1 += __shfl_xor(v1, o);
    v2 += __shfl_xor(v2, o); v3 += __shfl_xor(v3, o);
  }
  uint2 pk;
  pk.x = bfpack(q0.x, q1.x);
  pk.y = bfpack(q0.y, q1.y);
  *(uint2*)&packed[n * FF + 2 * lane] = pk;
  if (lane == 0) { ss[n] = v0; ss[NN + n] = v2; st[n] = v1; st[NN + n] = v3; }
}

// ---- K1c: packed[n][f] -> packedT2[n/32][h][f][n&31] bf16-pair words ----
__global__ __launch_bounds__(256) void k_tpose(const uint32_t* __restrict__ packed, uint32_t* __restrict__ pt2) {
  __shared__ uint32_t sb[32][129];
  const int t = threadIdx.x, c = blockIdx.x;
  const int nl = t >> 3, fb = (t & 7) * 16;
#pragma unroll
  for (int i = 0; i < 4; ++i) {
    uint4 v = *(const uint4*)&packed[(c * 32 + nl) * FF + fb + i * 4];
    sb[nl][fb + i * 4] = v.x; sb[nl][fb + i * 4 + 1] = v.y;
    sb[nl][fb + i * 4 + 2] = v.z; sb[nl][fb + i * 4 + 3] = v.w;
  }
  __syncthreads();
  const int h = t >> 7, f = t & 127;
  uint32_t wbuf[16];
#pragma unroll
  for (int p = 0; p < 16; ++p) {
    uint32_t a = sb[2 * p][f], b = sb[2 * p + 1][f];
    wbuf[p] = h ? ((a >> 16) | (b & 0xffff0000u)) : ((a & 0xffffu) | (b << 16));
  }
  uint32_t* dst = pt2 + ((c * 2 + h) * 128 + f) * 16;
#pragma unroll
  for (int i = 0; i < 4; ++i)
    *(uint4*)&dst[i * 4] = make_uint4(wbuf[i * 4], wbuf[i * 4 + 1], wbuf[i * 4 + 2], wbuf[i * 4 + 3]);
}

// ---- K2 (k_scan, r7-verified): copy mask -> out1, emit SORTED bitmask
// (word = m*256 + n/32, bit = n&31), colsum in registers + 2 atomics/thread. ----
__global__ __launch_bounds__(256) void k_scan(const float* __restrict__ mask, float* __restrict__ maskout,
                                              const float* __restrict__ ss, const float* __restrict__ st,
                                              float* __restrict__ csum, uint32_t* __restrict__ bitmask) {
  const int tid = threadIdx.x;
  const int lane = tid & 63, wv = tid >> 6;
  const int n = blockIdx.x * 256 + tid;
  const int m0 = blockIdx.y * 128;
  const int wbase = blockIdx.x * 8 + wv * 2;
  const float st0 = st[n], st1 = st[NN + n];
  const float ssA = ss[m0 + lane],      ssB = ss[m0 + 64 + lane];
  const float ssC = ss[NN + m0 + lane], ssD = ss[NN + m0 + 64 + lane];
  float c0 = 0.f, c1 = 0.f;

  for (int i = 0; i < 128; i += 8) {
    float v[8];
#pragma unroll
    for (int r = 0; r < 8; ++r)
      v[r] = __builtin_nontemporal_load(&mask[(size_t)(m0 + i + r) * NN + n]);
#pragma unroll
    for (int r = 0; r < 8; ++r) {
      const int m = m0 + i + r;
      __builtin_nontemporal_store(v[r], &maskout[(size_t)m * NN + n]);
      bool e = v[r] > -0.5e9f;
      unsigned long long bm = __ballot(e);
      if (lane == 0)
        *(uint2*)&bitmask[m * 256 + wbase] = make_uint2((uint32_t)bm, (uint32_t)(bm >> 32));
      const int ri = i + r;
      float s0 = __uint_as_float(__builtin_amdgcn_readlane(
                   __float_as_uint(ri < 64 ? ssA : ssB), ri & 63));
      float s1 = __uint_as_float(__builtin_amdgcn_readlane(
                   __float_as_uint(ri < 64 ? ssC : ssD), ri & 63));
      float w0 = __expf(lrelu(s0 + st0));
      float w1 = __expf(lrelu(s1 + st1));
      c0 += e ? w0 : 0.f;
      c1 += e ? w1 : 0.f;
    }
  }
  atomicAdd(&csum[n], c0);
  atomicAdd(&csum[NN + n], c1);
}

// ---- K2c: pack per-column table {st0, st1, 1/csum0, 1/csum1} ----
__global__ __launch_bounds__(256) void k_ntab(const float* __restrict__ st, const float* __restrict__ csum,
                                              float4* __restrict__ ntab) {
  int i = blockIdx.x * 256 + threadIdx.x;
  ntab[i] = make_float4(st[i], st[NN + i], 1.f / csum[i], 1.f / csum[NN + i]);
}

// ---- K3 v9: DENSE MFMA, SPLIT-K. Grid (256 m-tiles, 8 n-chunks), block 128 (2 waves).
// LDS exactly 20 KB -> 8 blocks/CU (16 waves). Fragment-ordered LDS layouts:
//   B2[h][ft][q][col][8] shorts, A2[h][mt][q][col][8] shorts
// -> every MFMA operand ds_read is base + lane*16B (conflict-free).
// Partial 32m x 128f result atomicAdd'ed into zero-init'ed vals. ----
__global__ __launch_bounds__(128) void k_vals(const uint32_t* __restrict__ bitmask, const uint32_t* __restrict__ pt2,
                                              const float4* __restrict__ ntab, const float* __restrict__ ss,
                                              float* __restrict__ vals) {
  __shared__ short B2[2][8][4][16][8];   // 16 KB
  __shared__ short A2[2][2][4][16][8];   //  4 KB
  const int t = threadIdx.x;
  const int lane = t & 63, wid = t >> 6;
  const int m0 = blockIdx.x * 32;
  const int nc = blockIdx.y;                   // n-chunk: 1024 n
  const int q = lane >> 4, col = lane & 15;
  const int n2 = t & 15, mg = t >> 4;          // A-build: n-pair, m-subgroup(0..7)
  const int tft = t >> 4, tcol = t & 15;       // B-stage: f-tile row = t

  float ssm0[4], ssm1[4];
#pragma unroll
  for (int p = 0; p < 4; ++p) {
    ssm0[p] = ss[m0 + mg + 8 * p];
    ssm1[p] = ss[NN + m0 + mg + 8 * p];
  }

  f32x4 acc[8];
#pragma unroll
  for (int i = 0; i < 8; ++i) acc[i] = (f32x4){0.f, 0.f, 0.f, 0.f};

  uint32_t* B2w = (uint32_t*)&B2[0][0][0][0][0];
  uint32_t* A2w = (uint32_t*)&A2[0][0][0][0][0];

  for (int s = 0; s < 32; ++s) {
    const int n0 = nc * 1024 + s * 32;
    const uint32_t* src = pt2 + (n0 >> 5) * 4096;   // [h][f][16 words]
    // ---- stage B: thread t owns f-row t for both heads; word 4k..4k+3 -> [q=k] slot ----
#pragma unroll
    for (int h = 0; h < 2; ++h) {
      const uint4* p4 = (const uint4*)&src[(h * 128 + t) * 16];
#pragma unroll
      for (int k = 0; k < 4; ++k) {
        uint4 v = p4[k];
        *(uint4*)&B2w[(((h * 8 + tft) * 4 + k) * 16 + tcol) * 4] = v;
      }
    }
    // ---- build A: 32m x 32n x 2h ----
    float4 na = ntab[n0 + 2 * n2];
    float4 nb = ntab[n0 + 2 * n2 + 1];
#pragma unroll
    for (int p = 0; p < 4; ++p) {
      const int ml = mg + 8 * p;
      const int mt = ml >> 4, mcol = ml & 15;
      uint32_t bw = bitmask[(size_t)(m0 + ml) * 256 + (n0 >> 5)];
      float e0a = __expf(lrelu(ssm0[p] + na.x)) * na.z;
      float e1a = __expf(lrelu(ssm1[p] + na.y)) * na.w;
      float e0b = __expf(lrelu(ssm0[p] + nb.x)) * nb.z;
      float e1b = __expf(lrelu(ssm1[p] + nb.y)) * nb.w;
      bool b0 = (bw >> (2 * n2)) & 1, b1 = (bw >> (2 * n2 + 1)) & 1;
      e0a = b0 ? e0a : 0.f; e1a = b0 ? e1a : 0.f;
      e0b = b1 ? e0b : 0.f; e1b = b1 ? e1b : 0.f;
      int base = ((0 * 2 + mt) * 4 + (n2 >> 2)) * 64 + mcol * 4 + (n2 & 3);
      A2w[base] = bfpack(e0a, e0b);
      A2w[base + 2 * 4 * 64] = bfpack(e1a, e1b);   // h=1 plane offset = 2 mt * 4 q * 64
    }
    __syncthreads();
    // ---- MFMA: wave wid -> m-tile wid; operand reads are lane-linear ----
    bf16x8 a0 = *(const bf16x8*)&A2[0][wid][q][col][0];
    bf16x8 a1 = *(const bf16x8*)&A2[1][wid][q][col][0];
#pragma unroll
    for (int ft = 0; ft < 8; ++ft) {
      bf16x8 b0 = *(const bf16x8*)&B2[0][ft][q][col][0];
      acc[ft] = __builtin_amdgcn_mfma_f32_16x16x32_bf16(a0, b0, acc[ft], 0, 0, 0);
      bf16x8 b1 = *(const bf16x8*)&B2[1][ft][q][col][0];
      acc[ft] = __builtin_amdgcn_mfma_f32_16x16x32_bf16(a1, b1, acc[ft], 0, 0, 0);
    }
    __syncthreads();
  }

  // ---- accumulate partial into vals (head mean = x0.5) ----
#pragma unroll
  for (int ft = 0; ft < 8; ++ft) {
#pragma unroll
    for (int r = 0; r < 4; ++r) {
      int mrow = m0 + wid * 16 + q * 4 + r;
      atomicAdd(&vals[mrow * FF + ft * 16 + col], 0.5f * acc[ft][r]);
    }
  }
}

// ---- K4: stats reduction over vals ----
__global__ __launch_bounds__(256) void k_stats(const float* __restrict__ vals, float* __restrict__ stats) {
  int i = blockIdx.x * 256 + threadIdx.x;
  float4 v = *(const float4*)&vals[i * 4];
  float s = v.x + v.y + v.z + v.w;
  float q = v.x * v.x + v.y * v.y + v.z * v.z + v.w * v.w;
#pragma unroll
  for (int o = 1; o < 64; o <<= 1) { s += __shfl_xor(s, o); q += __shfl_xor(q, o); }
  if ((threadIdx.x & 63) == 0) { atomicAdd(stats, s); atomicAdd(stats + 1, q); }
}

// ---- K5: instance-norm + residual + ELU ----
__global__ __launch_bounds__(256) void k_final(const float* __restrict__ vals, const float* __restrict__ resid,
                                               const float* __restrict__ stats, float* __restrict__ out) {
  int i = (blockIdx.x * 256 + threadIdx.x) * 4;
  float mu = stats[0] * (1.f / NF);
  float var = stats[1] * (1.f / NF) - mu * mu;
  float rs = rsqrtf(var + EPSI);
  float4 v = *(const float4*)&vals[i];
  float4 r = *(const float4*)&resid[i];
  float t0 = (v.x - mu) * rs + r.x;
  float t1 = (v.y - mu) * rs + r.y;
  float t2 = (v.z - mu) * rs + r.z;
  float t3 = (v.w - mu) * rs + r.w;
  float4 o;
  o.x = t0 > 0.f ? t0 : expm1f(t0);
  o.y = t1 > 0.f ? t1 : expm1f(t1);
  o.z = t2 > 0.f ? t2 : expm1f(t2);
  o.w = t3 > 0.f ? t3 : expm1f(t3);
  *(float4*)&out[i] = o;
}

extern "C" void kernel_launch(void* const* d_in, const int* in_sizes, int n_in,
                              void* d_out, int out_size, void* d_ws, size_t ws_size,
                              hipStream_t stream) {
  const float* x     = (const float*)d_in[0];
  const float* mask  = (const float*)d_in[1];
  const float* W     = (const float*)d_in[2];
  const float* a_src = (const float*)d_in[3];
  const float* a_tgt = (const float*)d_in[4];
  const float* wres  = (const float*)d_in[5];
  float* out = (float*)d_out;
  float* wsf = (float*)d_ws;

  float*    proj    = wsf + OFF_PROJ;
  uint32_t* bitmask = (uint32_t*)(wsf + OFF_PROJ);   // overlays proj after k_sprep
  float*    resid   = wsf + OFF_RESID;
  uint32_t* packed  = (uint32_t*)(wsf + OFF_PACKED);
  float*    ss      = wsf + OFF_SS;
  float*    st      = wsf + OFF_ST;
  float*    csum    = wsf + OFF_CSUM;
  float*    stats   = wsf + OFF_STATS;
  float4*   ntab    = (float4*)(wsf + OFF_NTAB);
  float*    vals    = wsf + OFF_VALS;
  float*    wt      = wsf + OFF_WT;
  uint32_t* pt2     = (uint32_t*)(wsf + OFF_PT2);

  (void)hipMemsetAsync(csum, 0, (2 * NN + 16) * sizeof(float), stream);
  (void)hipMemsetAsync(vals, 0, NF * sizeof(float), stream);

  hipLaunchKernelGGL(k_wt,    dim3(DIN * FF / 256), dim3(256), 0, stream, wres, wt);
  hipLaunchKernelGGL(k_gemm,  dim3(NN / 64, 3),     dim3(256), 0, stream, x, W, wt, proj, resid);
  hipLaunchKernelGGL(k_sprep, dim3(NN / 4),         dim3(256), 0, stream, proj, a_src, a_tgt, ss, st, packed);
  hipLaunchKernelGGL(k_tpose, dim3(NN / 32),        dim3(256), 0, stream, packed, pt2);
  hipLaunchKernelGGL(k_scan,  dim3(NN / 256, NN / 128), dim3(256), 0, stream, mask, out + NF, ss, st, csum, bitmask);
  hipLaunchKernelGGL(k_ntab,  dim3(NN / 256),       dim3(256), 0, stream, st, csum, ntab);
  hipLaunchKernelGGL(k_vals,  dim3(NN / 32, 8),     dim3(128), 0, stream, bitmask, pt2, ntab, ss, vals);
  hipLaunchKernelGGL(k_stats, dim3(NF / 1024),      dim3(256), 0, stream, vals, stats);
  hipLaunchKernelGGL(k_final, dim3(NF / 1024),      dim3(256), 0, stream, vals, resid, stats, out);
}

// Round 11
// 721.486 us; speedup vs baseline: 1.1895x; 1.0153x over previous
//
#include <hip/hip_runtime.h>
#include <stdint.h>

#define NN   8192
#define DIN  256
#define FF   128
#define NF   (NN*FF)          // 1048576
#define SLOPE 0.2f
#define EPSI  1e-5f

typedef float vf4 __attribute__((ext_vector_type(4)));
typedef short bf16x8 __attribute__((ext_vector_type(8)));
typedef float f32x4 __attribute__((ext_vector_type(4)));

// ---- workspace layout (float offsets) ----
#define OFF_PROJ   0                       // [2][N][F] f32 (k_gemm->k_sprep), then REUSED as bitmask [N][256] u32 (8 MB)
#define OFF_RESID  (2*NF)                  // [N][F] f32
#define OFF_PACKED (3*NF)                  // [N][F] u32: lo16=bf16(h0), hi16=bf16(h1)
#define OFF_SS     (4*NF)                  // s_src [2][N]
#define OFF_ST     (OFF_SS + 2*NN)         // s_tgt [2][N]
#define OFF_CSUM   (OFF_ST + 2*NN)         // colsum [2][N]
#define OFF_STATS  (OFF_CSUM + 2*NN)       // S, SS (padded to 16)
#define OFF_NTAB   (OFF_STATS + 16)        // float4[N] = {st0, st1, rcp0, rcp1}
#define OFF_VALS   (OFF_NTAB + 4*NN)       // [N][F] f32
#define OFF_WT     (OFF_VALS + NF)         // W_res^T [DIN][F]
#define OFF_PT2    (OFF_WT + DIN*FF)       // packedT2: [N/32][2][128][16] u32 (4 MB)
#define OFF_VPART  (OFF_PT2 + NF)          // vpart: [8][N][F] f32 (32 MB)

__device__ __forceinline__ float lrelu(float x) { return x >= 0.f ? x : SLOPE * x; }

__device__ __forceinline__ uint32_t bfpack(float a, float b) {
  uint32_t ua = __float_as_uint(a); ua += 0x7fffu + ((ua >> 16) & 1u);
  uint32_t ub = __float_as_uint(b); ub += 0x7fffu + ((ub >> 16) & 1u);
  return (ua >> 16) | (ub & 0xffff0000u);
}

// ---- K0: transpose W_res [F][DIN] -> Wt [DIN][F] ----
__global__ __launch_bounds__(256) void k_wt(const float* __restrict__ wres, float* __restrict__ wt) {
  int i = blockIdx.x * 256 + threadIdx.x;
  int d = i >> 7, f = i & 127;
  wt[i] = wres[f * DIN + d];
}

// ---- K1: 3 GEMMs M=8192 K=256 N=128 (heads 0,1 -> proj; y==2 -> resid) ----
__global__ __launch_bounds__(256) void k_gemm(const float* __restrict__ x, const float* __restrict__ Wh,
                                              const float* __restrict__ wt, float* __restrict__ proj,
                                              float* __restrict__ resid) {
  const int h = blockIdx.y;
  const float* __restrict__ Wsrc = (h < 2) ? (Wh + h * (DIN * FF)) : wt;
  float* __restrict__ outp = (h < 2) ? (proj + h * NF) : resid;
  const int row0 = blockIdx.x * 64;
  __shared__ float xs[64 * 68];
  const int tid = threadIdx.x;
  const int ft = tid & 15, rt = tid >> 4;
  const int f0 = ft * 8, r0 = rt * 4;
  float acc[4][8];
#pragma unroll
  for (int j = 0; j < 4; ++j)
#pragma unroll
    for (int k = 0; k < 8; ++k) acc[j][k] = 0.f;

  for (int kc = 0; kc < 4; ++kc) {
    const int d0 = kc * 64;
#pragma unroll
    for (int k2 = 0; k2 < 4; ++k2) {
      int i = tid * 4 + k2 * 1024;
      int r = i >> 6, dd = i & 63;
      *(float4*)&xs[r * 68 + dd] = *(const float4*)&x[(row0 + r) * DIN + d0 + dd];
    }
    __syncthreads();
#pragma unroll
    for (int g = 0; g < 16; ++g) {
      const int dd = g * 4;
      float xr[4][4];
#pragma unroll
      for (int j = 0; j < 4; ++j) {
        float4 t = *(const float4*)&xs[(r0 + j) * 68 + dd];
        xr[j][0] = t.x; xr[j][1] = t.y; xr[j][2] = t.z; xr[j][3] = t.w;
      }
#pragma unroll
      for (int i = 0; i < 4; ++i) {
        float4 wa = *(const float4*)&Wsrc[(d0 + dd + i) * FF + f0];
        float4 wb = *(const float4*)&Wsrc[(d0 + dd + i) * FF + f0 + 4];
#pragma unroll
        for (int j = 0; j < 4; ++j) {
          float xx = xr[j][i];
          acc[j][0] += xx * wa.x; acc[j][1] += xx * wa.y; acc[j][2] += xx * wa.z; acc[j][3] += xx * wa.w;
          acc[j][4] += xx * wb.x; acc[j][5] += xx * wb.y; acc[j][6] += xx * wb.z; acc[j][7] += xx * wb.w;
        }
      }
    }
    __syncthreads();
  }
#pragma unroll
  for (int j = 0; j < 4; ++j) {
    int row = row0 + r0 + j;
    *(float4*)&outp[row * FF + f0]     = make_float4(acc[j][0], acc[j][1], acc[j][2], acc[j][3]);
    *(float4*)&outp[row * FF + f0 + 4] = make_float4(acc[j][4], acc[j][5], acc[j][6], acc[j][7]);
  }
}

// ---- K1b: per-node dots s_src/s_tgt (both heads) + bf16 pack of proj ----
__global__ __launch_bounds__(256) void k_sprep(const float* __restrict__ proj, const float* __restrict__ a_src,
                                               const float* __restrict__ a_tgt, float* __restrict__ ss,
                                               float* __restrict__ st, uint32_t* __restrict__ packed) {
  int lane = threadIdx.x & 63, wid = threadIdx.x >> 6;
  int n = blockIdx.x * 4 + wid;
  float2 q0 = *(const float2*)&proj[n * FF + 2 * lane];
  float2 q1 = *(const float2*)&proj[NF + n * FF + 2 * lane];
  float2 as0 = *(const float2*)&a_src[2 * lane];
  float2 at0 = *(const float2*)&a_tgt[2 * lane];
  float2 as1 = *(const float2*)&a_src[FF + 2 * lane];
  float2 at1 = *(const float2*)&a_tgt[FF + 2 * lane];
  float v0 = q0.x * as0.x + q0.y * as0.y;
  float v1 = q0.x * at0.x + q0.y * at0.y;
  float v2 = q1.x * as1.x + q1.y * as1.y;
  float v3 = q1.x * at1.x + q1.y * at1.y;
#pragma unroll
  for (int o = 1; o < 64; o <<= 1) {
    v0 += __shfl_xor(v0, o); v1 += __shfl_xor(v1, o);
    v2 += __shfl_xor(v2, o); v3 += __shfl_xor(v3, o);
  }
  uint2 pk;
  pk.x = bfpack(q0.x, q1.x);
  pk.y = bfpack(q0.y, q1.y);
  *(uint2*)&packed[n * FF + 2 * lane] = pk;
  if (lane == 0) { ss[n] = v0; ss[NN + n] = v2; st[n] = v1; st[NN + n] = v3; }
}

// ---- K1c: packed[n][f] -> packedT2[n/32][h][f][n&31] bf16-pair words ----
__global__ __launch_bounds__(256) void k_tpose(const uint32_t* __restrict__ packed, uint32_t* __restrict__ pt2) {
  __shared__ uint32_t sb[32][129];
  const int t = threadIdx.x, c = blockIdx.x;
  const int nl = t >> 3, fb = (t & 7) * 16;
#pragma unroll
  for (int i = 0; i < 4; ++i) {
    uint4 v = *(const uint4*)&packed[(c * 32 + nl) * FF + fb + i * 4];
    sb[nl][fb + i * 4] = v.x; sb[nl][fb + i * 4 + 1] = v.y;
    sb[nl][fb + i * 4 + 2] = v.z; sb[nl][fb + i * 4 + 3] = v.w;
  }
  __syncthreads();
  const int h = t >> 7, f = t & 127;
  uint32_t wbuf[16];
#pragma unroll
  for (int p = 0; p < 16; ++p) {
    uint32_t a = sb[2 * p][f], b = sb[2 * p + 1][f];
    wbuf[p] = h ? ((a >> 16) | (b & 0xffff0000u)) : ((a & 0xffffu) | (b << 16));
  }
  uint32_t* dst = pt2 + ((c * 2 + h) * 128 + f) * 16;
#pragma unroll
  for (int i = 0; i < 4; ++i)
    *(uint4*)&dst[i * 4] = make_uint4(wbuf[i * 4], wbuf[i * 4 + 1], wbuf[i * 4 + 2], wbuf[i * 4 + 3]);
}

// ---- K2 (k_scan, r7-verified): copy mask -> out1, emit SORTED bitmask
// (word = m*256 + n/32, bit = n&31), colsum in registers + 2 atomics/thread. ----
__global__ __launch_bounds__(256) void k_scan(const float* __restrict__ mask, float* __restrict__ maskout,
                                              const float* __restrict__ ss, const float* __restrict__ st,
                                              float* __restrict__ csum, uint32_t* __restrict__ bitmask) {
  const int tid = threadIdx.x;
  const int lane = tid & 63, wv = tid >> 6;
  const int n = blockIdx.x * 256 + tid;
  const int m0 = blockIdx.y * 128;
  const int wbase = blockIdx.x * 8 + wv * 2;
  const float st0 = st[n], st1 = st[NN + n];
  const float ssA = ss[m0 + lane],      ssB = ss[m0 + 64 + lane];
  const float ssC = ss[NN + m0 + lane], ssD = ss[NN + m0 + 64 + lane];
  float c0 = 0.f, c1 = 0.f;

  for (int i = 0; i < 128; i += 8) {
    float v[8];
#pragma unroll
    for (int r = 0; r < 8; ++r)
      v[r] = __builtin_nontemporal_load(&mask[(size_t)(m0 + i + r) * NN + n]);
#pragma unroll
    for (int r = 0; r < 8; ++r) {
      const int m = m0 + i + r;
      __builtin_nontemporal_store(v[r], &maskout[(size_t)m * NN + n]);
      bool e = v[r] > -0.5e9f;
      unsigned long long bm = __ballot(e);
      if (lane == 0)
        *(uint2*)&bitmask[m * 256 + wbase] = make_uint2((uint32_t)bm, (uint32_t)(bm >> 32));
      const int ri = i + r;
      float s0 = __uint_as_float(__builtin_amdgcn_readlane(
                   __float_as_uint(ri < 64 ? ssA : ssB), ri & 63));
      float s1 = __uint_as_float(__builtin_amdgcn_readlane(
                   __float_as_uint(ri < 64 ? ssC : ssD), ri & 63));
      float w0 = __expf(lrelu(s0 + st0));
      float w1 = __expf(lrelu(s1 + st1));
      c0 += e ? w0 : 0.f;
      c1 += e ? w1 : 0.f;
    }
  }
  atomicAdd(&csum[n], c0);
  atomicAdd(&csum[NN + n], c1);
}

// ---- K2c: pack per-column table {st0, st1, 1/csum0, 1/csum1} ----
__global__ __launch_bounds__(256) void k_ntab(const float* __restrict__ st, const float* __restrict__ csum,
                                              float4* __restrict__ ntab) {
  int i = blockIdx.x * 256 + threadIdx.x;
  ntab[i] = make_float4(st[i], st[NN + i], 1.f / csum[i], 1.f / csum[NN + i]);
}

// ---- K3 v10: DENSE MFMA, SPLIT-K into PRIVATE PARTIALS (no atomics).
// Grid (128 m-tiles of 64, 8 n-chunks), block 128 (2 waves). LDS 24 KB.
// Wave m-tile = 32 rows (2 m-frags): per step 20 ds_read_b128 / 32 MFMA.
// Fragment-ordered LDS: B2[h][ft][q][col][8], A2[h][mt][q][col][8] (lane-linear reads). ----
__global__ __launch_bounds__(128) void k_vals(const uint32_t* __restrict__ bitmask, const uint32_t* __restrict__ pt2,
                                              const float4* __restrict__ ntab, const float* __restrict__ ss,
                                              float* __restrict__ vpart) {
  __shared__ short B2[2][8][4][16][8];   // 16 KB
  __shared__ short A2[2][4][4][16][8];   //  8 KB (64 m-rows)
  const int t = threadIdx.x;
  const int lane = t & 63, wid = t >> 6;
  const int m0 = blockIdx.x * 64;
  const int nc = blockIdx.y;                   // n-chunk: 1024 n
  const int q = lane >> 4, col = lane & 15;
  const int n2 = t & 15, mg = t >> 4;          // A-build: n-pair, m-subgroup(0..7)

  float ssm0[8], ssm1[8];
#pragma unroll
  for (int p = 0; p < 8; ++p) {
    ssm0[p] = ss[m0 + mg + 8 * p];
    ssm1[p] = ss[NN + m0 + mg + 8 * p];
  }

  f32x4 acc[2][8];
#pragma unroll
  for (int i = 0; i < 2; ++i)
#pragma unroll
    for (int j = 0; j < 8; ++j) acc[i][j] = (f32x4){0.f, 0.f, 0.f, 0.f};

  uint32_t* B2w = (uint32_t*)&B2[0][0][0][0][0];
  uint32_t* A2w = (uint32_t*)&A2[0][0][0][0][0];

  for (int s = 0; s < 32; ++s) {
    const int n0 = nc * 1024 + s * 32;
    const uint32_t* src = pt2 + (nc * 32 + s) * 4096;   // [h][f][16 words]
    // ---- stage B: thread t owns f-row t for both heads ----
#pragma unroll
    for (int h = 0; h < 2; ++h) {
      const uint4* p4 = (const uint4*)&src[(h * 128 + t) * 16];
#pragma unroll
      for (int k = 0; k < 4; ++k) {
        uint4 v = p4[k];
        *(uint4*)&B2w[(((h * 8 + (t >> 4)) * 4 + k) * 16 + (t & 15)) * 4] = v;
      }
    }
    // ---- build A: 64m x 32n x 2h ----
    float4 na = ntab[n0 + 2 * n2];
    float4 nb = ntab[n0 + 2 * n2 + 1];
#pragma unroll
    for (int p = 0; p < 8; ++p) {
      const int ml = mg + 8 * p;
      const int mt = ml >> 4, mcol = ml & 15;
      uint32_t bw = bitmask[(size_t)(m0 + ml) * 256 + (n0 >> 5)];
      float e0a = __expf(lrelu(ssm0[p] + na.x)) * na.z;
      float e1a = __expf(lrelu(ssm1[p] + na.y)) * na.w;
      float e0b = __expf(lrelu(ssm0[p] + nb.x)) * nb.z;
      float e1b = __expf(lrelu(ssm1[p] + nb.y)) * nb.w;
      bool b0 = (bw >> (2 * n2)) & 1, b1 = (bw >> (2 * n2 + 1)) & 1;
      e0a = b0 ? e0a : 0.f; e1a = b0 ? e1a : 0.f;
      e0b = b1 ? e0b : 0.f; e1b = b1 ? e1b : 0.f;
      int base = (mt * 4 + (n2 >> 2)) * 64 + mcol * 4 + (n2 & 3);
      A2w[base] = bfpack(e0a, e0b);
      A2w[base + 1024] = bfpack(e1a, e1b);     // h=1 plane = 4 mt * 4 q * 64 words
    }
    __syncthreads();
    // ---- MFMA: wave wid -> m-frags wid*2, wid*2+1 ----
    bf16x8 a00 = *(const bf16x8*)&A2[0][wid * 2][q][col][0];
    bf16x8 a01 = *(const bf16x8*)&A2[0][wid * 2 + 1][q][col][0];
    bf16x8 a10 = *(const bf16x8*)&A2[1][wid * 2][q][col][0];
    bf16x8 a11 = *(const bf16x8*)&A2[1][wid * 2 + 1][q][col][0];
#pragma unroll
    for (int ft = 0; ft < 8; ++ft) {
      bf16x8 b0 = *(const bf16x8*)&B2[0][ft][q][col][0];
      acc[0][ft] = __builtin_amdgcn_mfma_f32_16x16x32_bf16(a00, b0, acc[0][ft], 0, 0, 0);
      acc[1][ft] = __builtin_amdgcn_mfma_f32_16x16x32_bf16(a01, b0, acc[1][ft], 0, 0, 0);
      bf16x8 b1 = *(const bf16x8*)&B2[1][ft][q][col][0];
      acc[0][ft] = __builtin_amdgcn_mfma_f32_16x16x32_bf16(a10, b1, acc[0][ft], 0, 0, 0);
      acc[1][ft] = __builtin_amdgcn_mfma_f32_16x16x32_bf16(a11, b1, acc[1][ft], 0, 0, 0);
    }
    __syncthreads();
  }

  // ---- plain stores into private partial (head mean = x0.5) ----
  float* dst = vpart + (size_t)nc * NF;
#pragma unroll
  for (int mt2 = 0; mt2 < 2; ++mt2)
#pragma unroll
    for (int ft = 0; ft < 8; ++ft)
#pragma unroll
      for (int r = 0; r < 4; ++r) {
        int mrow = m0 + (wid * 2 + mt2) * 16 + q * 4 + r;
        dst[mrow * FF + ft * 16 + col] = 0.5f * acc[mt2][ft][r];
      }
}

// ---- K4: reduce 8 partials -> vals + stats ----
__global__ __launch_bounds__(256) void k_stats(const float* __restrict__ vpart, float* __restrict__ vals,
                                               float* __restrict__ stats) {
  int i = (blockIdx.x * 256 + threadIdx.x) * 4;
  float4 a = make_float4(0.f, 0.f, 0.f, 0.f);
#pragma unroll
  for (int p = 0; p < 8; ++p) {
    float4 v = *(const float4*)&vpart[(size_t)p * NF + i];
    a.x += v.x; a.y += v.y; a.z += v.z; a.w += v.w;
  }
  *(float4*)&vals[i] = a;
  float s = a.x + a.y + a.z + a.w;
  float q = a.x * a.x + a.y * a.y + a.z * a.z + a.w * a.w;
#pragma unroll
  for (int o = 1; o < 64; o <<= 1) { s += __shfl_xor(s, o); q += __shfl_xor(q, o); }
  if ((threadIdx.x & 63) == 0) { atomicAdd(stats, s); atomicAdd(stats + 1, q); }
}

// ---- K5: instance-norm + residual + ELU ----
__global__ __launch_bounds__(256) void k_final(const float* __restrict__ vals, const float* __restrict__ resid,
                                               const float* __restrict__ stats, float* __restrict__ out) {
  int i = (blockIdx.x * 256 + threadIdx.x) * 4;
  float mu = stats[0] * (1.f / NF);
  float var = stats[1] * (1.f / NF) - mu * mu;
  float rs = rsqrtf(var + EPSI);
  float4 v = *(const float4*)&vals[i];
  float4 r = *(const float4*)&resid[i];
  float t0 = (v.x - mu) * rs + r.x;
  float t1 = (v.y - mu) * rs + r.y;
  float t2 = (v.z - mu) * rs + r.z;
  float t3 = (v.w - mu) * rs + r.w;
  float4 o;
  o.x = t0 > 0.f ? t0 : expm1f(t0);
  o.y = t1 > 0.f ? t1 : expm1f(t1);
  o.z = t2 > 0.f ? t2 : expm1f(t2);
  o.w = t3 > 0.f ? t3 : expm1f(t3);
  *(float4*)&out[i] = o;
}

extern "C" void kernel_launch(void* const* d_in, const int* in_sizes, int n_in,
                              void* d_out, int out_size, void* d_ws, size_t ws_size,
                              hipStream_t stream) {
  const float* x     = (const float*)d_in[0];
  const float* mask  = (const float*)d_in[1];
  const float* W     = (const float*)d_in[2];
  const float* a_src = (const float*)d_in[3];
  const float* a_tgt = (const float*)d_in[4];
  const float* wres  = (const float*)d_in[5];
  float* out = (float*)d_out;
  float* wsf = (float*)d_ws;

  float*    proj    = wsf + OFF_PROJ;
  uint32_t* bitmask = (uint32_t*)(wsf + OFF_PROJ);   // overlays proj after k_sprep
  float*    resid   = wsf + OFF_RESID;
  uint32_t* packed  = (uint32_t*)(wsf + OFF_PACKED);
  float*    ss      = wsf + OFF_SS;
  float*    st      = wsf + OFF_ST;
  float*    csum    = wsf + OFF_CSUM;
  float*    stats   = wsf + OFF_STATS;
  float4*   ntab    = (float4*)(wsf + OFF_NTAB);
  float*    vals    = wsf + OFF_VALS;
  float*    wt      = wsf + OFF_WT;
  uint32_t* pt2     = (uint32_t*)(wsf + OFF_PT2);
  float*    vpart   = wsf + OFF_VPART;

  (void)hipMemsetAsync(csum, 0, (2 * NN + 16) * sizeof(float), stream);

  hipLaunchKernelGGL(k_wt,    dim3(DIN * FF / 256), dim3(256), 0, stream, wres, wt);
  hipLaunchKernelGGL(k_gemm,  dim3(NN / 64, 3),     dim3(256), 0, stream, x, W, wt, proj, resid);
  hipLaunchKernelGGL(k_sprep, dim3(NN / 4),         dim3(256), 0, stream, proj, a_src, a_tgt, ss, st, packed);
  hipLaunchKernelGGL(k_tpose, dim3(NN / 32),        dim3(256), 0, stream, packed, pt2);
  hipLaunchKernelGGL(k_scan,  dim3(NN / 256, NN / 128), dim3(256), 0, stream, mask, out + NF, ss, st, csum, bitmask);
  hipLaunchKernelGGL(k_ntab,  dim3(NN / 256),       dim3(256), 0, stream, st, csum, ntab);
  hipLaunchKernelGGL(k_vals,  dim3(NN / 64, 8),     dim3(128), 0, stream, bitmask, pt2, ntab, ss, vpart);
  hipLaunchKernelGGL(k_stats, dim3(NF / 1024),      dim3(256), 0, stream, vpart, vals, stats);
  hipLaunchKernelGGL(k_final, dim3(NF / 1024),      dim3(256), 0, stream, vals, resid, stats, out);
}